// Round 2
// baseline (2183.014 us; speedup 1.0000x reference)
//
#include <hip/hip_runtime.h>
#include <math.h>

#define N_NODES 100000
#define DIM 64
#define E_REL 1600000
#define E_QQ 1000000

// ---------------------------------------------------------------------------
// Degree accumulation: c[0..N) = deg(src_pos), c[N..2N) = deg(dst_pos),
// c[2N..3N) = deg(src_neg), c[3N..4N) = deg(dst_neg)   (as float counts)
// ---------------------------------------------------------------------------
__global__ __launch_bounds__(256) void deg_kernel(
    const int* __restrict__ sp, const int* __restrict__ dp,
    const int* __restrict__ sn, const int* __restrict__ dn,
    float* __restrict__ c) {
  int i = blockIdx.x * 256 + threadIdx.x;
  if (i >= E_REL) return;
  atomicAdd(&c[sp[i]], 1.0f);
  atomicAdd(&c[N_NODES + dp[i]], 1.0f);
  atomicAdd(&c[2 * N_NODES + sn[i]], 1.0f);
  atomicAdd(&c[3 * N_NODES + dn[i]], 1.0f);
}

// c[i] = deg>0 ? rsqrt(deg) : 0
__global__ __launch_bounds__(256) void cnorm_kernel(float* __restrict__ c) {
  int i = blockIdx.x * 256 + threadIdx.x;
  if (i >= 4 * N_NODES) return;
  float d = c[i];
  c[i] = d > 0.0f ? rsqrtf(d) : 0.0f;
}

// ---------------------------------------------------------------------------
// Y[row] = csrc[row] * (X[row] @ W)        (thread-per-row, W in LDS)
// ---------------------------------------------------------------------------
__global__ __launch_bounds__(256) void gemm_in(
    const float* __restrict__ X, const float* __restrict__ W,
    const float* __restrict__ csrc, float* __restrict__ Y) {
  __shared__ float Ws[64 * 64];
  for (int t = threadIdx.x; t < 64 * 64; t += 256) Ws[t] = W[t];
  __syncthreads();
  int row = blockIdx.x * 256 + threadIdx.x;
  if (row >= N_NODES) return;
  const float4* xr = (const float4*)(X + (size_t)row * 64);
  float acc[64];
#pragma unroll
  for (int j = 0; j < 64; j++) acc[j] = 0.0f;
#pragma unroll
  for (int k4 = 0; k4 < 16; k4++) {
    float4 xv = xr[k4];
    const float* w0 = &Ws[(k4 * 4 + 0) * 64];
    const float* w1 = &Ws[(k4 * 4 + 1) * 64];
    const float* w2 = &Ws[(k4 * 4 + 2) * 64];
    const float* w3 = &Ws[(k4 * 4 + 3) * 64];
#pragma unroll
    for (int j = 0; j < 64; j++)
      acc[j] += xv.x * w0[j] + xv.y * w1[j] + xv.z * w2[j] + xv.w * w3[j];
  }
  float s = csrc[row];
  float4* yr = (float4*)(Y + (size_t)row * 64);
#pragma unroll
  for (int j4 = 0; j4 < 16; j4++) {
    float4 o;
    o.x = s * acc[j4 * 4 + 0];
    o.y = s * acc[j4 * 4 + 1];
    o.z = s * acc[j4 * 4 + 2];
    o.w = s * acc[j4 * 4 + 3];
    yr[j4] = o;
  }
}

// ---------------------------------------------------------------------------
// Y[row] = csrc[row] * ( relu(AGG[row]*cdst[row] + b0) @ W )
// (fuses conv1 epilogue + conv2 input transform + conv2 weight)
// ---------------------------------------------------------------------------
__global__ __launch_bounds__(256) void gemm_mid(
    const float* __restrict__ AGG, const float* __restrict__ W,
    const float* __restrict__ b0, const float* __restrict__ cdst,
    const float* __restrict__ csrc, float* __restrict__ Y) {
  __shared__ float Ws[64 * 64];
  __shared__ float bs[64];
  for (int t = threadIdx.x; t < 64 * 64; t += 256) Ws[t] = W[t];
  if (threadIdx.x < 64) bs[threadIdx.x] = b0[threadIdx.x];
  __syncthreads();
  int row = blockIdx.x * 256 + threadIdx.x;
  if (row >= N_NODES) return;
  float cd = cdst[row];
  const float4* ar = (const float4*)(AGG + (size_t)row * 64);
  float acc[64];
#pragma unroll
  for (int j = 0; j < 64; j++) acc[j] = 0.0f;
#pragma unroll
  for (int k4 = 0; k4 < 16; k4++) {
    float4 av = ar[k4];
    float t0 = fmaxf(av.x * cd + bs[k4 * 4 + 0], 0.0f);
    float t1 = fmaxf(av.y * cd + bs[k4 * 4 + 1], 0.0f);
    float t2 = fmaxf(av.z * cd + bs[k4 * 4 + 2], 0.0f);
    float t3 = fmaxf(av.w * cd + bs[k4 * 4 + 3], 0.0f);
    const float* w0 = &Ws[(k4 * 4 + 0) * 64];
    const float* w1 = &Ws[(k4 * 4 + 1) * 64];
    const float* w2 = &Ws[(k4 * 4 + 2) * 64];
    const float* w3 = &Ws[(k4 * 4 + 3) * 64];
#pragma unroll
    for (int j = 0; j < 64; j++)
      acc[j] += t0 * w0[j] + t1 * w1[j] + t2 * w2[j] + t3 * w3[j];
  }
  float s = csrc[row];
  float4* yr = (float4*)(Y + (size_t)row * 64);
#pragma unroll
  for (int j4 = 0; j4 < 16; j4++) {
    float4 o;
    o.x = s * acc[j4 * 4 + 0];
    o.y = s * acc[j4 * 4 + 1];
    o.z = s * acc[j4 * 4 + 2];
    o.w = s * acc[j4 * 4 + 3];
    yr[j4] = o;
  }
}

// ---------------------------------------------------------------------------
// AGG[dst[e]][f] += Y[src[e]][f]  — one (edge,feature) item per thread,
// wave = exactly one edge (64 lanes), coalesced gather + coalesced atomics.
// ---------------------------------------------------------------------------
__global__ __launch_bounds__(256) void scatter_kernel(
    const float* __restrict__ Y, const int* __restrict__ src,
    const int* __restrict__ dst, float* __restrict__ AGG) {
  const int total = E_REL * 64;
  int stride = gridDim.x * 256;
  for (int idx = blockIdx.x * 256 + threadIdx.x; idx < total; idx += stride) {
    int e = idx >> 6;
    int f = idx & 63;
    int s = src[e];
    int d = dst[e];
    float v = Y[(size_t)s * 64 + f];
    atomicAdd(&AGG[(size_t)d * 64 + f], v);
  }
}

// ---------------------------------------------------------------------------
// mode 0: Z[i] = relu(AGG[i]*cdst[row] + b1[f])
// mode 1: Z[i] -= relu(AGG[i]*cdst[row] + b1[f])
// ---------------------------------------------------------------------------
__global__ __launch_bounds__(256) void zfin_kernel(
    const float* __restrict__ AGG, const float* __restrict__ b1,
    const float* __restrict__ cdst, float* __restrict__ Z, int mode) {
  int i = blockIdx.x * 256 + threadIdx.x;
  if (i >= N_NODES * 64) return;
  int row = i >> 6;
  int f = i & 63;
  float v = fmaxf(AGG[i] * cdst[row] + b1[f], 0.0f);
  if (mode == 0)
    Z[i] = v;
  else
    Z[i] -= v;
}

// ---------------------------------------------------------------------------
// probs[e] = sigmoid(concat(Z[s], Z[d]) @ Wc + bc)   (Wc: [128,2])
// src half uses Wc rows 0..63 (LDS idx 0..127),
// dst half uses Wc rows 64..127 (LDS idx 128..255).
// ---------------------------------------------------------------------------
__global__ __launch_bounds__(256) void classify_kernel(
    const float* __restrict__ Z, const int* __restrict__ ei,
    const float* __restrict__ Wc, const float* __restrict__ bc,
    float* __restrict__ out) {
  __shared__ float Wcs[256];
  __shared__ float bcs[2];
  Wcs[threadIdx.x] = Wc[threadIdx.x];
  if (threadIdx.x < 2) bcs[threadIdx.x] = bc[threadIdx.x];
  __syncthreads();
  int e = blockIdx.x * 256 + threadIdx.x;
  if (e >= E_QQ) return;
  int s = ei[e];
  int d = ei[E_QQ + e];
  float a0 = bcs[0], a1 = bcs[1];
  const float4* zs = (const float4*)(Z + (size_t)s * 64);
#pragma unroll
  for (int k4 = 0; k4 < 16; k4++) {
    float4 v = zs[k4];
    int r = k4 * 4;  // Wc row 0..63
    a0 += v.x * Wcs[(r + 0) * 2 + 0] + v.y * Wcs[(r + 1) * 2 + 0] +
          v.z * Wcs[(r + 2) * 2 + 0] + v.w * Wcs[(r + 3) * 2 + 0];
    a1 += v.x * Wcs[(r + 0) * 2 + 1] + v.y * Wcs[(r + 1) * 2 + 1] +
          v.z * Wcs[(r + 2) * 2 + 1] + v.w * Wcs[(r + 3) * 2 + 1];
  }
  const float4* zd = (const float4*)(Z + (size_t)d * 64);
#pragma unroll
  for (int k4 = 0; k4 < 16; k4++) {
    float4 v = zd[k4];
    int r = 64 + k4 * 4;  // Wc row 64..127
    a0 += v.x * Wcs[(r + 0) * 2 + 0] + v.y * Wcs[(r + 1) * 2 + 0] +
          v.z * Wcs[(r + 2) * 2 + 0] + v.w * Wcs[(r + 3) * 2 + 0];
    a1 += v.x * Wcs[(r + 0) * 2 + 1] + v.y * Wcs[(r + 1) * 2 + 1] +
          v.z * Wcs[(r + 2) * 2 + 1] + v.w * Wcs[(r + 3) * 2 + 1];
  }
  out[(size_t)e * 2 + 0] = 1.0f / (1.0f + __expf(-a0));
  out[(size_t)e * 2 + 1] = 1.0f / (1.0f + __expf(-a1));
}

extern "C" void kernel_launch(void* const* d_in, const int* in_sizes, int n_in,
                              void* d_out, int out_size, void* d_ws,
                              size_t ws_size, hipStream_t stream) {
  const float* x   = (const float*)d_in[0];
  const float* W0p = (const float*)d_in[1];
  const float* b0p = (const float*)d_in[2];
  const float* W0n = (const float*)d_in[3];
  const float* b0n = (const float*)d_in[4];
  const float* W1p = (const float*)d_in[5];
  const float* b1p = (const float*)d_in[6];
  const float* W1n = (const float*)d_in[7];
  const float* b1n = (const float*)d_in[8];
  const float* Wc  = (const float*)d_in[9];
  const float* bc  = (const float*)d_in[10];
  const int* sp = (const int*)d_in[11];
  const int* dp = (const int*)d_in[12];
  const int* sn = (const int*)d_in[13];
  const int* dn = (const int*)d_in[14];
  const int* ei = (const int*)d_in[15];

  float* ws  = (float*)d_ws;
  float* c   = ws;                            // 4N floats
  float* y   = ws + 4 * N_NODES;              // N*64
  float* agg = y + (size_t)N_NODES * 64;      // N*64
  float* z     = (float*)d_out;               // N*64
  float* probs = z + (size_t)N_NODES * 64;    // E_Q*2

  const float* csp = c;
  const float* cdp = c + N_NODES;
  const float* csn = c + 2 * N_NODES;
  const float* cdn = c + 3 * N_NODES;

  const size_t aggBytes = (size_t)N_NODES * 64 * sizeof(float);
  const int gemmGrid = (N_NODES + 255) / 256;
  const int elemGrid = (N_NODES * 64 + 255) / 256;

  // degrees -> norms
  hipMemsetAsync(c, 0, 4 * N_NODES * sizeof(float), stream);
  deg_kernel<<<(E_REL + 255) / 256, 256, 0, stream>>>(sp, dp, sn, dn, c);
  cnorm_kernel<<<(4 * N_NODES + 255) / 256, 256, 0, stream>>>(c);

  // ---- POS relation ----
  gemm_in<<<gemmGrid, 256, 0, stream>>>(x, W0p, csp, y);
  hipMemsetAsync(agg, 0, aggBytes, stream);
  scatter_kernel<<<8192, 256, 0, stream>>>(y, sp, dp, agg);
  gemm_mid<<<gemmGrid, 256, 0, stream>>>(agg, W1p, b0p, cdp, csp, y);
  hipMemsetAsync(agg, 0, aggBytes, stream);
  scatter_kernel<<<8192, 256, 0, stream>>>(y, sp, dp, agg);
  zfin_kernel<<<elemGrid, 256, 0, stream>>>(agg, b1p, cdp, z, 0);

  // ---- NEG relation ----
  gemm_in<<<gemmGrid, 256, 0, stream>>>(x, W0n, csn, y);
  hipMemsetAsync(agg, 0, aggBytes, stream);
  scatter_kernel<<<8192, 256, 0, stream>>>(y, sn, dn, agg);
  gemm_mid<<<gemmGrid, 256, 0, stream>>>(agg, W1n, b0n, cdn, csn, y);
  hipMemsetAsync(agg, 0, aggBytes, stream);
  scatter_kernel<<<8192, 256, 0, stream>>>(y, sn, dn, agg);
  zfin_kernel<<<elemGrid, 256, 0, stream>>>(agg, b1n, cdn, z, 1);

  // ---- classifier ----
  classify_kernel<<<(E_QQ + 255) / 256, 256, 0, stream>>>(z, ei, Wc, bc, probs);
}

// Round 3
// 1436.643 us; speedup vs baseline: 1.5195x; 1.5195x over previous
//
#include <hip/hip_runtime.h>
#include <math.h>

#define N_NODES 100000
#define DIM 64
#define E_REL 1600000
#define E_QQ 1000000
#define CHUNK 1024
#define NB 98  // ceil(N_NODES / CHUNK)

// ---------------------------------------------------------------------------
// Degree accumulation: c[0..N) = deg(src_pos), c[N..2N) = deg(dst_pos),
// c[2N..3N) = deg(src_neg), c[3N..4N) = deg(dst_neg)   (as float counts)
// ---------------------------------------------------------------------------
__global__ __launch_bounds__(256) void deg_kernel(
    const int* __restrict__ sp, const int* __restrict__ dp,
    const int* __restrict__ sn, const int* __restrict__ dn,
    float* __restrict__ c) {
  int i = blockIdx.x * 256 + threadIdx.x;
  if (i >= E_REL) return;
  atomicAdd(&c[sp[i]], 1.0f);
  atomicAdd(&c[N_NODES + dp[i]], 1.0f);
  atomicAdd(&c[2 * N_NODES + sn[i]], 1.0f);
  atomicAdd(&c[3 * N_NODES + dn[i]], 1.0f);
}

// c[i] = deg>0 ? rsqrt(deg) : 0
__global__ __launch_bounds__(256) void cnorm_kernel(float* __restrict__ c) {
  int i = blockIdx.x * 256 + threadIdx.x;
  if (i >= 4 * N_NODES) return;
  float d = c[i];
  c[i] = d > 0.0f ? rsqrtf(d) : 0.0f;
}

// ---------------------------------------------------------------------------
// Prefix-sum pipeline over float degree counts -> int CSR offsets
// ---------------------------------------------------------------------------
__global__ __launch_bounds__(256) void scan_sum(const float* __restrict__ cnt,
                                               int* __restrict__ partial) {
  __shared__ int ls[256];
  int b = blockIdx.x, t = threadIdx.x;
  int base = b * CHUNK + t * 4;
  int s = 0;
#pragma unroll
  for (int k = 0; k < 4; k++) {
    int i = base + k;
    if (i < N_NODES) s += (int)cnt[i];
  }
  ls[t] = s;
  __syncthreads();
  for (int off = 1; off < 256; off <<= 1) {
    int v = (t >= off) ? ls[t - off] : 0;
    __syncthreads();
    ls[t] += v;
    __syncthreads();
  }
  if (t == 255) partial[b] = ls[255];
}

__global__ void scan_part(int* __restrict__ partial, int* __restrict__ offs) {
  if (threadIdx.x == 0) {
    int run = 0;
    for (int b = 0; b < NB; b++) {
      int v = partial[b];
      partial[b] = run;
      run += v;
    }
    offs[N_NODES] = run;
  }
}

__global__ __launch_bounds__(256) void scan_write(const float* __restrict__ cnt,
                                                  const int* __restrict__ partial,
                                                  int* __restrict__ offs) {
  __shared__ int ls[256];
  int b = blockIdx.x, t = threadIdx.x;
  int base = b * CHUNK + t * 4;
  int d[4];
  int s = 0;
#pragma unroll
  for (int k = 0; k < 4; k++) {
    int i = base + k;
    d[k] = (i < N_NODES) ? (int)cnt[i] : 0;
    s += d[k];
  }
  ls[t] = s;
  __syncthreads();
  for (int off = 1; off < 256; off <<= 1) {
    int v = (t >= off) ? ls[t - off] : 0;
    __syncthreads();
    ls[t] += v;
    __syncthreads();
  }
  int run = partial[b] + (ls[t] - s);
#pragma unroll
  for (int k = 0; k < 4; k++) {
    int i = base + k;
    if (i < N_NODES) {
      offs[i] = run;
      run += d[k];
    }
  }
}

// sorted[offs[dst[e]] + slot] = src[e]
__global__ __launch_bounds__(256) void csr_fill(
    const int* __restrict__ src, const int* __restrict__ dst,
    const int* __restrict__ offs, int* __restrict__ cur,
    int* __restrict__ sorted) {
  int e = blockIdx.x * 256 + threadIdx.x;
  if (e >= E_REL) return;
  int d = dst[e];
  int p = atomicAdd(&cur[d], 1);
  sorted[offs[d] + p] = src[e];
}

// ---------------------------------------------------------------------------
// Y[row] = csrc[row] * (X[row] @ W)        (thread-per-row, W in LDS)
// ---------------------------------------------------------------------------
__global__ __launch_bounds__(256) void gemm_in(
    const float* __restrict__ X, const float* __restrict__ W,
    const float* __restrict__ csrc, float* __restrict__ Y) {
  __shared__ float Ws[64 * 64];
  for (int t = threadIdx.x; t < 64 * 64; t += 256) Ws[t] = W[t];
  __syncthreads();
  int row = blockIdx.x * 256 + threadIdx.x;
  if (row >= N_NODES) return;
  const float4* xr = (const float4*)(X + (size_t)row * 64);
  float acc[64];
#pragma unroll
  for (int j = 0; j < 64; j++) acc[j] = 0.0f;
#pragma unroll
  for (int k4 = 0; k4 < 16; k4++) {
    float4 xv = xr[k4];
    const float* w0 = &Ws[(k4 * 4 + 0) * 64];
    const float* w1 = &Ws[(k4 * 4 + 1) * 64];
    const float* w2 = &Ws[(k4 * 4 + 2) * 64];
    const float* w3 = &Ws[(k4 * 4 + 3) * 64];
#pragma unroll
    for (int j = 0; j < 64; j++)
      acc[j] += xv.x * w0[j] + xv.y * w1[j] + xv.z * w2[j] + xv.w * w3[j];
  }
  float s = csrc[row];
  float4* yr = (float4*)(Y + (size_t)row * 64);
#pragma unroll
  for (int j4 = 0; j4 < 16; j4++) {
    float4 o;
    o.x = s * acc[j4 * 4 + 0];
    o.y = s * acc[j4 * 4 + 1];
    o.z = s * acc[j4 * 4 + 2];
    o.w = s * acc[j4 * 4 + 3];
    yr[j4] = o;
  }
}

// ---------------------------------------------------------------------------
// CSR aggregation, one wave per node, lane = feature.
// acc = sum_{e in in(node)} Y[src(e)][lane]
// v = relu(acc * cdst[node] + bias[lane])
// MODE 0: out = v      MODE 1: out -= v
// ---------------------------------------------------------------------------
template <int MODE>
__global__ __launch_bounds__(256) void gather_agg(
    const float* __restrict__ Y, const int* __restrict__ offs,
    const int* __restrict__ sorted, const float* __restrict__ cdst,
    const float* __restrict__ bias, float* __restrict__ out) {
  int wid = (blockIdx.x * 256 + threadIdx.x) >> 6;
  int lane = threadIdx.x & 63;
  if (wid >= N_NODES) return;
  int beg = offs[wid];
  int end = offs[wid + 1];
  float acc = 0.0f;
  for (int base = beg; base < end; base += 64) {
    int cnt = end - base;
    if (cnt > 64) cnt = 64;
    int sv = (base + lane < end) ? sorted[base + lane] : 0;
    for (int j = 0; j < cnt; j++) {
      int s = __shfl(sv, j);
      acc += Y[(size_t)s * 64 + lane];
    }
  }
  float v = fmaxf(acc * cdst[wid] + bias[lane], 0.0f);
  if (MODE == 0)
    out[(size_t)wid * 64 + lane] = v;
  else
    out[(size_t)wid * 64 + lane] -= v;
}

// ---------------------------------------------------------------------------
// probs[e] = sigmoid(concat(Z[s], Z[d]) @ Wc + bc)   (Wc: [128,2])
// ---------------------------------------------------------------------------
__global__ __launch_bounds__(256) void classify_kernel(
    const float* __restrict__ Z, const int* __restrict__ ei,
    const float* __restrict__ Wc, const float* __restrict__ bc,
    float* __restrict__ out) {
  __shared__ float Wcs[256];
  __shared__ float bcs[2];
  Wcs[threadIdx.x] = Wc[threadIdx.x];
  if (threadIdx.x < 2) bcs[threadIdx.x] = bc[threadIdx.x];
  __syncthreads();
  int e = blockIdx.x * 256 + threadIdx.x;
  if (e >= E_QQ) return;
  int s = ei[e];
  int d = ei[E_QQ + e];
  float a0 = bcs[0], a1 = bcs[1];
  const float4* zs = (const float4*)(Z + (size_t)s * 64);
#pragma unroll
  for (int k4 = 0; k4 < 16; k4++) {
    float4 v = zs[k4];
    int r = k4 * 4;  // Wc rows 0..63
    a0 += v.x * Wcs[(r + 0) * 2 + 0] + v.y * Wcs[(r + 1) * 2 + 0] +
          v.z * Wcs[(r + 2) * 2 + 0] + v.w * Wcs[(r + 3) * 2 + 0];
    a1 += v.x * Wcs[(r + 0) * 2 + 1] + v.y * Wcs[(r + 1) * 2 + 1] +
          v.z * Wcs[(r + 2) * 2 + 1] + v.w * Wcs[(r + 3) * 2 + 1];
  }
  const float4* zd = (const float4*)(Z + (size_t)d * 64);
#pragma unroll
  for (int k4 = 0; k4 < 16; k4++) {
    float4 v = zd[k4];
    int r = 64 + k4 * 4;  // Wc rows 64..127
    a0 += v.x * Wcs[(r + 0) * 2 + 0] + v.y * Wcs[(r + 1) * 2 + 0] +
          v.z * Wcs[(r + 2) * 2 + 0] + v.w * Wcs[(r + 3) * 2 + 0];
    a1 += v.x * Wcs[(r + 0) * 2 + 1] + v.y * Wcs[(r + 1) * 2 + 1] +
          v.z * Wcs[(r + 2) * 2 + 1] + v.w * Wcs[(r + 3) * 2 + 1];
  }
  out[(size_t)e * 2 + 0] = 1.0f / (1.0f + __expf(-a0));
  out[(size_t)e * 2 + 1] = 1.0f / (1.0f + __expf(-a1));
}

extern "C" void kernel_launch(void* const* d_in, const int* in_sizes, int n_in,
                              void* d_out, int out_size, void* d_ws,
                              size_t ws_size, hipStream_t stream) {
  const float* x   = (const float*)d_in[0];
  const float* W0p = (const float*)d_in[1];
  const float* b0p = (const float*)d_in[2];
  const float* W0n = (const float*)d_in[3];
  const float* b0n = (const float*)d_in[4];
  const float* W1p = (const float*)d_in[5];
  const float* b1p = (const float*)d_in[6];
  const float* W1n = (const float*)d_in[7];
  const float* b1n = (const float*)d_in[8];
  const float* Wc  = (const float*)d_in[9];
  const float* bc  = (const float*)d_in[10];
  const int* sp = (const int*)d_in[11];
  const int* dp = (const int*)d_in[12];
  const int* sn = (const int*)d_in[13];
  const int* dn = (const int*)d_in[14];
  const int* ei = (const int*)d_in[15];

  // workspace layout
  float* c = (float*)d_ws;                       // 4N floats (1.6 MB)
  float* y = c + 4 * N_NODES;                    // N*64 (25.6 MB)
  float* h = y + (size_t)N_NODES * 64;           // N*64 (25.6 MB)
  int* offs_p  = (int*)(h + (size_t)N_NODES * 64);  // N+1
  int* offs_n  = offs_p + (N_NODES + 1);            // N+1
  int* cur     = offs_n + (N_NODES + 1);            // N
  int* partial = cur + N_NODES;                     // 128
  int* sorted  = partial + 128;                     // E_REL (6.4 MB)

  float* z     = (float*)d_out;                  // N*64
  float* probs = z + (size_t)N_NODES * 64;       // E_Q*2

  const float* csp = c;
  const float* cdp = c + N_NODES;
  const float* csn = c + 2 * N_NODES;
  const float* cdn = c + 3 * N_NODES;

  const int gemmGrid = (N_NODES + 255) / 256;
  const int aggGrid = (N_NODES * 64 + 255) / 256;
  const int edgeGrid = (E_REL + 255) / 256;

  // degrees (float counts)
  hipMemsetAsync(c, 0, 4 * N_NODES * sizeof(float), stream);
  deg_kernel<<<edgeGrid, 256, 0, stream>>>(sp, dp, sn, dn, c);

  // CSR offsets for both relations (reads raw counts, before cnorm)
  scan_sum<<<NB, 256, 0, stream>>>(c + N_NODES, partial);
  scan_part<<<1, 64, 0, stream>>>(partial, offs_p);
  scan_write<<<NB, 256, 0, stream>>>(c + N_NODES, partial, offs_p);
  scan_sum<<<NB, 256, 0, stream>>>(c + 3 * N_NODES, partial);
  scan_part<<<1, 64, 0, stream>>>(partial, offs_n);
  scan_write<<<NB, 256, 0, stream>>>(c + 3 * N_NODES, partial, offs_n);

  // norms
  cnorm_kernel<<<(4 * N_NODES + 255) / 256, 256, 0, stream>>>(c);

  // ---- POS relation ----
  hipMemsetAsync(cur, 0, N_NODES * sizeof(int), stream);
  csr_fill<<<edgeGrid, 256, 0, stream>>>(sp, dp, offs_p, cur, sorted);
  gemm_in<<<gemmGrid, 256, 0, stream>>>(x, W0p, csp, y);
  gather_agg<0><<<aggGrid, 256, 0, stream>>>(y, offs_p, sorted, cdp, b0p, h);
  gemm_in<<<gemmGrid, 256, 0, stream>>>(h, W1p, csp, y);
  gather_agg<0><<<aggGrid, 256, 0, stream>>>(y, offs_p, sorted, cdp, b1p, z);

  // ---- NEG relation ----
  hipMemsetAsync(cur, 0, N_NODES * sizeof(int), stream);
  csr_fill<<<edgeGrid, 256, 0, stream>>>(sn, dn, offs_n, cur, sorted);
  gemm_in<<<gemmGrid, 256, 0, stream>>>(x, W0n, csn, y);
  gather_agg<0><<<aggGrid, 256, 0, stream>>>(y, offs_n, sorted, cdn, b0n, h);
  gemm_in<<<gemmGrid, 256, 0, stream>>>(h, W1n, csn, y);
  gather_agg<1><<<aggGrid, 256, 0, stream>>>(y, offs_n, sorted, cdn, b1n, z);

  // ---- classifier ----
  classify_kernel<<<(E_QQ + 255) / 256, 256, 0, stream>>>(z, ei, Wc, bc, probs);
}

// Round 4
// 1069.616 us; speedup vs baseline: 2.0409x; 1.3431x over previous
//
#include <hip/hip_runtime.h>
#include <hip/hip_fp16.h>
#include <math.h>

#define N_NODES 100000
#define DIM 64
#define E_REL 1600000
#define E_QQ 1000000
#define PAD 48  // max in-degree capacity; Poisson(16) P(>=48) ~ 1e-11

__device__ inline unsigned pack_h2(float a, float b) {
  __half2 h = __floats2half2_rn(a, b);
  return *reinterpret_cast<unsigned*>(&h);
}

// ---------------------------------------------------------------------------
// Fused CSR build + histograms for one relation:
//  - float src-degree histogram into chist (for c_src norm)
//  - int cursor atomic on cur[dst] -> slot; sorted[dst*PAD+slot] = src
//  cur[] ends as the dst in-degree (used inline as rsqrt norm later).
// ---------------------------------------------------------------------------
__global__ __launch_bounds__(256) void csr_fill(
    const int* __restrict__ src, const int* __restrict__ dst,
    float* __restrict__ chist, int* __restrict__ cur,
    int* __restrict__ sorted) {
  int e = blockIdx.x * 256 + threadIdx.x;
  if (e >= E_REL) return;
  int s = src[e];
  int d = dst[e];
  atomicAdd(&chist[s], 1.0f);
  int p = atomicAdd(&cur[d], 1);
  if (p < PAD) sorted[d * PAD + p] = s;
}

// c[i] = deg>0 ? rsqrt(deg) : 0   (src norms for both relations, 2N entries)
__global__ __launch_bounds__(256) void cnorm_kernel(float* __restrict__ c,
                                                    int n) {
  int i = blockIdx.x * 256 + threadIdx.x;
  if (i >= n) return;
  float d = c[i];
  c[i] = d > 0.0f ? rsqrtf(d) : 0.0f;
}

// ---------------------------------------------------------------------------
// Y[row] = fp16( csrc[row] * (X[row] @ W) )   thread-per-row, W in LDS
// ---------------------------------------------------------------------------
__global__ __launch_bounds__(256) void gemm_in_h(
    const float* __restrict__ X, const float* __restrict__ W,
    const float* __restrict__ csrc, __half* __restrict__ Y) {
  __shared__ float Ws[64 * 64];
  for (int t = threadIdx.x; t < 64 * 64; t += 256) Ws[t] = W[t];
  __syncthreads();
  int row = blockIdx.x * 256 + threadIdx.x;
  if (row >= N_NODES) return;
  const float4* xr = (const float4*)(X + (size_t)row * 64);
  float acc[64];
#pragma unroll
  for (int j = 0; j < 64; j++) acc[j] = 0.0f;
#pragma unroll
  for (int k4 = 0; k4 < 16; k4++) {
    float4 xv = xr[k4];
    const float* w0 = &Ws[(k4 * 4 + 0) * 64];
    const float* w1 = &Ws[(k4 * 4 + 1) * 64];
    const float* w2 = &Ws[(k4 * 4 + 2) * 64];
    const float* w3 = &Ws[(k4 * 4 + 3) * 64];
#pragma unroll
    for (int j = 0; j < 64; j++)
      acc[j] += xv.x * w0[j] + xv.y * w1[j] + xv.z * w2[j] + xv.w * w3[j];
  }
  float s = csrc[row];
  uint4* yr = (uint4*)(Y + (size_t)row * 64);
#pragma unroll
  for (int j8 = 0; j8 < 8; j8++) {
    uint4 u;
    u.x = pack_h2(s * acc[j8 * 8 + 0], s * acc[j8 * 8 + 1]);
    u.y = pack_h2(s * acc[j8 * 8 + 2], s * acc[j8 * 8 + 3]);
    u.z = pack_h2(s * acc[j8 * 8 + 4], s * acc[j8 * 8 + 5]);
    u.w = pack_h2(s * acc[j8 * 8 + 6], s * acc[j8 * 8 + 7]);
    yr[j8] = u;
  }
}

// ---------------------------------------------------------------------------
// Fused: conv1 aggregation + epilogue + conv2 input GEMM.
// One wave per node, lane = feature.
//   agg  = sum_{s in in(node)} Y[s][lane]
//   h    = relu(agg * rsqrt(deg) + b0[lane])      (stage h row in LDS)
//   Y2[node][lane] = fp16( csrc[node] * sum_k h[k] * W1[k][lane] )
// ---------------------------------------------------------------------------
__global__ __launch_bounds__(256) void gather_mid(
    const __half* __restrict__ Y, const int* __restrict__ cur,
    const int* __restrict__ sorted, const float* __restrict__ b0,
    const float* __restrict__ csrc, const float* __restrict__ W1,
    __half* __restrict__ Y2) {
  __shared__ float Ws[64 * 64];
  __shared__ float hs[4][64];
  for (int t = threadIdx.x; t < 64 * 64; t += 256) Ws[t] = W1[t];
  __syncthreads();
  int wid = (blockIdx.x * 256 + threadIdx.x) >> 6;
  int lane = threadIdx.x & 63;
  int wslot = threadIdx.x >> 6;
  if (wid >= N_NODES) return;
  int deg = cur[wid];
  int cnt = deg < PAD ? deg : PAD;
  int sv = (lane < cnt) ? sorted[wid * PAD + lane] : 0;
  float acc = 0.0f;
  for (int j = 0; j < cnt; j++) {
    int s = __shfl(sv, j);
    acc += __half2float(Y[(size_t)s * 64 + lane]);
  }
  float cd = deg > 0 ? rsqrtf((float)deg) : 0.0f;
  hs[wslot][lane] = fmaxf(acc * cd + b0[lane], 0.0f);
  // same-wave LDS write->read: compiler inserts lgkmcnt wait; no barrier needed
  float acc2 = 0.0f;
#pragma unroll 8
  for (int k = 0; k < 64; k++) acc2 += hs[wslot][k] * Ws[k * 64 + lane];
  Y2[(size_t)wid * 64 + lane] = __float2half(csrc[wid] * acc2);
}

// ---------------------------------------------------------------------------
// Final aggregation + epilogue into z (fp32 output).
// MODE 0: z = relu(...)      MODE 1: z -= relu(...)
// ---------------------------------------------------------------------------
template <int MODE>
__global__ __launch_bounds__(256) void gather_fin(
    const __half* __restrict__ Y2, const int* __restrict__ cur,
    const int* __restrict__ sorted, const float* __restrict__ b1,
    float* __restrict__ z) {
  int wid = (blockIdx.x * 256 + threadIdx.x) >> 6;
  int lane = threadIdx.x & 63;
  if (wid >= N_NODES) return;
  int deg = cur[wid];
  int cnt = deg < PAD ? deg : PAD;
  int sv = (lane < cnt) ? sorted[wid * PAD + lane] : 0;
  float acc = 0.0f;
  for (int j = 0; j < cnt; j++) {
    int s = __shfl(sv, j);
    acc += __half2float(Y2[(size_t)s * 64 + lane]);
  }
  float cd = deg > 0 ? rsqrtf((float)deg) : 0.0f;
  float v = fmaxf(acc * cd + b1[lane], 0.0f);
  if (MODE == 0)
    z[(size_t)wid * 64 + lane] = v;
  else
    z[(size_t)wid * 64 + lane] -= v;
}

// ---------------------------------------------------------------------------
// probs[e] = sigmoid(concat(Z[s], Z[d]) @ Wc + bc)   (Wc: [128,2])
// ---------------------------------------------------------------------------
__global__ __launch_bounds__(256) void classify_kernel(
    const float* __restrict__ Z, const int* __restrict__ ei,
    const float* __restrict__ Wc, const float* __restrict__ bc,
    float* __restrict__ out) {
  __shared__ float Wcs[256];
  __shared__ float bcs[2];
  Wcs[threadIdx.x] = Wc[threadIdx.x];
  if (threadIdx.x < 2) bcs[threadIdx.x] = bc[threadIdx.x];
  __syncthreads();
  int e = blockIdx.x * 256 + threadIdx.x;
  if (e >= E_QQ) return;
  int s = ei[e];
  int d = ei[E_QQ + e];
  float a0 = bcs[0], a1 = bcs[1];
  const float4* zs = (const float4*)(Z + (size_t)s * 64);
#pragma unroll
  for (int k4 = 0; k4 < 16; k4++) {
    float4 v = zs[k4];
    int r = k4 * 4;  // Wc rows 0..63
    a0 += v.x * Wcs[(r + 0) * 2 + 0] + v.y * Wcs[(r + 1) * 2 + 0] +
          v.z * Wcs[(r + 2) * 2 + 0] + v.w * Wcs[(r + 3) * 2 + 0];
    a1 += v.x * Wcs[(r + 0) * 2 + 1] + v.y * Wcs[(r + 1) * 2 + 1] +
          v.z * Wcs[(r + 2) * 2 + 1] + v.w * Wcs[(r + 3) * 2 + 1];
  }
  const float4* zd = (const float4*)(Z + (size_t)d * 64);
#pragma unroll
  for (int k4 = 0; k4 < 16; k4++) {
    float4 v = zd[k4];
    int r = 64 + k4 * 4;  // Wc rows 64..127
    a0 += v.x * Wcs[(r + 0) * 2 + 0] + v.y * Wcs[(r + 1) * 2 + 0] +
          v.z * Wcs[(r + 2) * 2 + 0] + v.w * Wcs[(r + 3) * 2 + 0];
    a1 += v.x * Wcs[(r + 0) * 2 + 1] + v.y * Wcs[(r + 1) * 2 + 1] +
          v.z * Wcs[(r + 2) * 2 + 1] + v.w * Wcs[(r + 3) * 2 + 1];
  }
  out[(size_t)e * 2 + 0] = 1.0f / (1.0f + __expf(-a0));
  out[(size_t)e * 2 + 1] = 1.0f / (1.0f + __expf(-a1));
}

extern "C" void kernel_launch(void* const* d_in, const int* in_sizes, int n_in,
                              void* d_out, int out_size, void* d_ws,
                              size_t ws_size, hipStream_t stream) {
  const float* x   = (const float*)d_in[0];
  const float* W0p = (const float*)d_in[1];
  const float* b0p = (const float*)d_in[2];
  const float* W0n = (const float*)d_in[3];
  const float* b0n = (const float*)d_in[4];
  const float* W1p = (const float*)d_in[5];
  const float* b1p = (const float*)d_in[6];
  const float* W1n = (const float*)d_in[7];
  const float* b1n = (const float*)d_in[8];
  const float* Wc  = (const float*)d_in[9];
  const float* bc  = (const float*)d_in[10];
  const int* sp = (const int*)d_in[11];
  const int* dp = (const int*)d_in[12];
  const int* sn = (const int*)d_in[13];
  const int* dn = (const int*)d_in[14];
  const int* ei = (const int*)d_in[15];

  // workspace layout (~46.4 MB)
  float* c     = (float*)d_ws;                   // 2N floats: csp | csn
  int*   cur_p = (int*)(c + 2 * N_NODES);        // N ints (pos in-degree)
  int*   cur_n = cur_p + N_NODES;                // N ints (neg in-degree)
  __half* A    = (__half*)(cur_n + N_NODES);     // N*64 fp16
  __half* B    = A + (size_t)N_NODES * 64;       // N*64 fp16
  int* sorted  = (int*)(B + (size_t)N_NODES * 64);  // N*PAD ints (shared)

  float* z     = (float*)d_out;                  // N*64 fp32
  float* probs = z + (size_t)N_NODES * 64;       // E_Q*2 fp32

  const float* csp = c;
  const float* csn = c + N_NODES;

  const int fillGrid = (E_REL + 255) / 256;
  const int gemmGrid = (N_NODES + 255) / 256;
  const int aggGrid  = (N_NODES * 64 + 255) / 256;

  // zero c + cur_p + cur_n (contiguous, 1.6 MB)
  hipMemsetAsync(c, 0, (2 * N_NODES + 2 * N_NODES) * sizeof(float), stream);

  // ---- POS relation ----
  csr_fill<<<fillGrid, 256, 0, stream>>>(sp, dp, c, cur_p, sorted);
  cnorm_kernel<<<(N_NODES + 255) / 256, 256, 0, stream>>>(c, N_NODES);
  gemm_in_h<<<gemmGrid, 256, 0, stream>>>(x, W0p, csp, A);
  gather_mid<<<aggGrid, 256, 0, stream>>>(A, cur_p, sorted, b0p, csp, W1p, B);
  gather_fin<0><<<aggGrid, 256, 0, stream>>>(B, cur_p, sorted, b1p, z);

  // ---- NEG relation ---- (sorted reused; pos consumers are done)
  csr_fill<<<fillGrid, 256, 0, stream>>>(sn, dn, c + N_NODES, cur_n, sorted);
  cnorm_kernel<<<(N_NODES + 255) / 256, 256, 0, stream>>>(c + N_NODES, N_NODES);
  gemm_in_h<<<gemmGrid, 256, 0, stream>>>(x, W0n, csn, A);
  gather_mid<<<aggGrid, 256, 0, stream>>>(A, cur_n, sorted, b0n, csn, W1n, B);
  gather_fin<1><<<aggGrid, 256, 0, stream>>>(B, cur_n, sorted, b1n, z);

  // ---- classifier ----
  classify_kernel<<<(E_QQ + 255) / 256, 256, 0, stream>>>(z, ei, Wc, bc, probs);
}

// Round 5
// 916.370 us; speedup vs baseline: 2.3822x; 1.1672x over previous
//
#include <hip/hip_runtime.h>
#include <hip/hip_fp16.h>
#include <math.h>

#define N_NODES 100000
#define DIM 64
#define E_REL 1600000
#define E_QQ 1000000

#define NBUCK 196      // ceil(100000 / 512) node buckets of 512
#define BCAP 9216      // capacity per bucket; expected 8192, +11 sigma slack
#define CHUNK_E 8192   // edges per phase-1 block
#define P1_BLOCKS ((E_REL + CHUNK_E - 1) / CHUNK_E)  // 196

// ---------------------------------------------------------------------------
// Phase 1: bin edges by dst-bucket (packed (dlocal<<17)|src) and by src-bucket
// (raw src). Per-block LDS counts; ~2*NBUCK global atomics per block reserve
// space; placement via LDS cursors + plain (write-back) stores.
// ---------------------------------------------------------------------------
__global__ __launch_bounds__(256) void bin_edges(
    const int* __restrict__ src, const int* __restrict__ dst,
    int* __restrict__ gcur_d, int* __restrict__ gcur_s,
    unsigned* __restrict__ bin_d, unsigned* __restrict__ bin_s) {
  __shared__ int cd[NBUCK];
  __shared__ int cs[NBUCK];
  int t = threadIdx.x;
  for (int i = t; i < NBUCK; i += 256) { cd[i] = 0; cs[i] = 0; }
  __syncthreads();
  int e0 = blockIdx.x * CHUNK_E;
  int e1 = e0 + CHUNK_E;
  if (e1 > E_REL) e1 = E_REL;
  // pass A: count
  for (int e = e0 + t; e < e1; e += 256) {
    atomicAdd(&cd[dst[e] >> 9], 1);
    atomicAdd(&cs[src[e] >> 9], 1);
  }
  __syncthreads();
  // reserve global space; cd/cs become running cursors (start at base)
  for (int i = t; i < NBUCK; i += 256) {
    cd[i] = atomicAdd(&gcur_d[i], cd[i]);
    cs[i] = atomicAdd(&gcur_s[i], cs[i]);
  }
  __syncthreads();
  // pass B: place (edge reads are L2-hot)
  for (int e = e0 + t; e < e1; e += 256) {
    int s = src[e];
    int d = dst[e];
    int bd = d >> 9;
    int bs = s >> 9;
    int pd = atomicAdd(&cd[bd], 1);
    int ps = atomicAdd(&cs[bs], 1);
    if ((unsigned)pd < BCAP)
      bin_d[(size_t)bd * BCAP + pd] = (unsigned)(((d & 511) << 17) | s);
    if ((unsigned)ps < BCAP)
      bin_s[(size_t)bs * BCAP + ps] = (unsigned)s;
  }
}

// ---------------------------------------------------------------------------
// Phase 2 (dst): one block per bucket (512 nodes). LDS node histogram ->
// scan -> compact per-node src lists + offs/deg (all coalesced/L2-local).
// ---------------------------------------------------------------------------
__global__ __launch_bounds__(256) void build_csr(
    const unsigned* __restrict__ bin_d, const int* __restrict__ gcur_d,
    int* __restrict__ offs, int* __restrict__ degv, int* __restrict__ srclist) {
  __shared__ int cnt[512];
  __shared__ int off0[512];
  __shared__ int curv[512];
  __shared__ int ls[256];
  int b = blockIdx.x, t = threadIdx.x;
  cnt[t] = 0;
  cnt[t + 256] = 0;
  __syncthreads();
  int n = gcur_d[b];
  if (n > BCAP) n = BCAP;
  const unsigned* be = bin_d + (size_t)b * BCAP;
  for (int i = t; i < n; i += 256) atomicAdd(&cnt[be[i] >> 17], 1);
  __syncthreads();
  // exclusive scan over 512 (pairs per thread, Hillis-Steele over 256)
  int c0 = cnt[2 * t], c1 = cnt[2 * t + 1];
  ls[t] = c0 + c1;
  __syncthreads();
  for (int off = 1; off < 256; off <<= 1) {
    int v = (t >= off) ? ls[t - off] : 0;
    __syncthreads();
    ls[t] += v;
    __syncthreads();
  }
  int base = ls[t] - (c0 + c1);
  off0[2 * t] = base;
  off0[2 * t + 1] = base + c0;
  curv[2 * t] = base;
  curv[2 * t + 1] = base + c0;
  __syncthreads();
  // place src ids compactly per node
  for (int i = t; i < n; i += 256) {
    unsigned p = be[i];
    int dl = p >> 17;
    int pos = atomicAdd(&curv[dl], 1);
    srclist[(size_t)b * BCAP + pos] = (int)(p & 0x1FFFF);
  }
  __syncthreads();
  int node0 = b << 9;
  for (int i = t; i < 512; i += 256) {
    int node = node0 + i;
    if (node < N_NODES) {
      offs[node] = b * BCAP + off0[i];
      degv[node] = cnt[i];
    }
  }
}

// ---------------------------------------------------------------------------
// Phase 2 (src): LDS histogram per bucket -> csrc = rsqrt(outdeg) (or 0)
// ---------------------------------------------------------------------------
__global__ __launch_bounds__(256) void src_hist(
    const unsigned* __restrict__ bin_s, const int* __restrict__ gcur_s,
    float* __restrict__ csrc) {
  __shared__ int h[512];
  int b = blockIdx.x, t = threadIdx.x;
  h[t] = 0;
  h[t + 256] = 0;
  __syncthreads();
  int n = gcur_s[b];
  if (n > BCAP) n = BCAP;
  const unsigned* be = bin_s + (size_t)b * BCAP;
  for (int i = t; i < n; i += 256) atomicAdd(&h[be[i] & 511], 1);
  __syncthreads();
  int node0 = b << 9;
  for (int i = t; i < 512; i += 256) {
    int node = node0 + i;
    if (node < N_NODES) {
      int d = h[i];
      csrc[node] = d > 0 ? rsqrtf((float)d) : 0.0f;
    }
  }
}

__device__ inline unsigned pack_h2(float a, float b) {
  __half2 h = __floats2half2_rn(a, b);
  return *reinterpret_cast<unsigned*>(&h);
}

// ---------------------------------------------------------------------------
// Y[row] = fp16( csrc[row] * (X[row] @ W) )   thread-per-row, W in LDS
// ---------------------------------------------------------------------------
__global__ __launch_bounds__(256) void gemm_in_h(
    const float* __restrict__ X, const float* __restrict__ W,
    const float* __restrict__ csrc, __half* __restrict__ Y) {
  __shared__ float Ws[64 * 64];
  for (int t = threadIdx.x; t < 64 * 64; t += 256) Ws[t] = W[t];
  __syncthreads();
  int row = blockIdx.x * 256 + threadIdx.x;
  if (row >= N_NODES) return;
  const float4* xr = (const float4*)(X + (size_t)row * 64);
  float acc[64];
#pragma unroll
  for (int j = 0; j < 64; j++) acc[j] = 0.0f;
#pragma unroll
  for (int k4 = 0; k4 < 16; k4++) {
    float4 xv = xr[k4];
    const float* w0 = &Ws[(k4 * 4 + 0) * 64];
    const float* w1 = &Ws[(k4 * 4 + 1) * 64];
    const float* w2 = &Ws[(k4 * 4 + 2) * 64];
    const float* w3 = &Ws[(k4 * 4 + 3) * 64];
#pragma unroll
    for (int j = 0; j < 64; j++)
      acc[j] += xv.x * w0[j] + xv.y * w1[j] + xv.z * w2[j] + xv.w * w3[j];
  }
  float s = csrc[row];
  uint4* yr = (uint4*)(Y + (size_t)row * 64);
#pragma unroll
  for (int j8 = 0; j8 < 8; j8++) {
    uint4 u;
    u.x = pack_h2(s * acc[j8 * 8 + 0], s * acc[j8 * 8 + 1]);
    u.y = pack_h2(s * acc[j8 * 8 + 2], s * acc[j8 * 8 + 3]);
    u.z = pack_h2(s * acc[j8 * 8 + 4], s * acc[j8 * 8 + 5]);
    u.w = pack_h2(s * acc[j8 * 8 + 6], s * acc[j8 * 8 + 7]);
    yr[j8] = u;
  }
}

// ---------------------------------------------------------------------------
// Fused: conv1 aggregation + epilogue + conv2 input GEMM.
// One wave per node, lane = feature.
// ---------------------------------------------------------------------------
__global__ __launch_bounds__(256) void gather_mid(
    const __half* __restrict__ Y, const int* __restrict__ offs,
    const int* __restrict__ degv, const int* __restrict__ srclist,
    const float* __restrict__ b0, const float* __restrict__ csrc,
    const float* __restrict__ W1, __half* __restrict__ Y2) {
  __shared__ float Ws[64 * 64];
  __shared__ float hs[4][64];
  for (int t = threadIdx.x; t < 64 * 64; t += 256) Ws[t] = W1[t];
  __syncthreads();
  int wid = (blockIdx.x * 256 + threadIdx.x) >> 6;
  int lane = threadIdx.x & 63;
  int wslot = threadIdx.x >> 6;
  if (wid >= N_NODES) return;
  int beg = offs[wid];
  int deg = degv[wid];
  float acc = 0.0f;
  for (int base = 0; base < deg; base += 64) {
    int rem = deg - base;
    int cnt = rem < 64 ? rem : 64;
    int sv = (base + lane < deg) ? srclist[beg + base + lane] : 0;
    for (int j = 0; j < cnt; j++) {
      int s = __shfl(sv, j);
      acc += __half2float(Y[(size_t)s * 64 + lane]);
    }
  }
  float cd = deg > 0 ? rsqrtf((float)deg) : 0.0f;
  hs[wslot][lane] = fmaxf(acc * cd + b0[lane], 0.0f);
  float acc2 = 0.0f;
#pragma unroll 8
  for (int k = 0; k < 64; k++) acc2 += hs[wslot][k] * Ws[k * 64 + lane];
  Y2[(size_t)wid * 64 + lane] = __float2half(csrc[wid] * acc2);
}

// ---------------------------------------------------------------------------
// Final aggregation + epilogue into z (fp32 output).
// MODE 0: z = relu(...)    MODE 1: z -= relu(...), also emit fp16 copy zh
// ---------------------------------------------------------------------------
template <int MODE>
__global__ __launch_bounds__(256) void gather_fin(
    const __half* __restrict__ Y2, const int* __restrict__ offs,
    const int* __restrict__ degv, const int* __restrict__ srclist,
    const float* __restrict__ b1, float* __restrict__ z,
    __half* __restrict__ zh) {
  int wid = (blockIdx.x * 256 + threadIdx.x) >> 6;
  int lane = threadIdx.x & 63;
  if (wid >= N_NODES) return;
  int beg = offs[wid];
  int deg = degv[wid];
  float acc = 0.0f;
  for (int base = 0; base < deg; base += 64) {
    int rem = deg - base;
    int cnt = rem < 64 ? rem : 64;
    int sv = (base + lane < deg) ? srclist[beg + base + lane] : 0;
    for (int j = 0; j < cnt; j++) {
      int s = __shfl(sv, j);
      acc += __half2float(Y2[(size_t)s * 64 + lane]);
    }
  }
  float cd = deg > 0 ? rsqrtf((float)deg) : 0.0f;
  float v = fmaxf(acc * cd + b1[lane], 0.0f);
  size_t idx = (size_t)wid * 64 + lane;
  if (MODE == 0) {
    z[idx] = v;
  } else {
    float r = z[idx] - v;
    z[idx] = r;
    zh[idx] = __float2half(r);
  }
}

// ---------------------------------------------------------------------------
// probs[e] = sigmoid(concat(Zh[s], Zh[d]) @ Wc + bc)   (fp16 z gathers)
// ---------------------------------------------------------------------------
__global__ __launch_bounds__(256) void classify_kernel(
    const __half* __restrict__ Zh, const int* __restrict__ ei,
    const float* __restrict__ Wc, const float* __restrict__ bc,
    float* __restrict__ out) {
  __shared__ float Wcs[256];
  __shared__ float bcs[2];
  Wcs[threadIdx.x] = Wc[threadIdx.x];
  if (threadIdx.x < 2) bcs[threadIdx.x] = bc[threadIdx.x];
  __syncthreads();
  int e = blockIdx.x * 256 + threadIdx.x;
  if (e >= E_QQ) return;
  int s = ei[e];
  int d = ei[E_QQ + e];
  float a0 = bcs[0], a1 = bcs[1];
  const __half2* zs = (const __half2*)(Zh + (size_t)s * 64);
#pragma unroll
  for (int k = 0; k < 32; k++) {
    float2 v = __half22float2(zs[k]);
    a0 += v.x * Wcs[(2 * k) * 2 + 0] + v.y * Wcs[(2 * k + 1) * 2 + 0];
    a1 += v.x * Wcs[(2 * k) * 2 + 1] + v.y * Wcs[(2 * k + 1) * 2 + 1];
  }
  const __half2* zd = (const __half2*)(Zh + (size_t)d * 64);
#pragma unroll
  for (int k = 0; k < 32; k++) {
    float2 v = __half22float2(zd[k]);
    a0 += v.x * Wcs[128 + (2 * k) * 2 + 0] + v.y * Wcs[128 + (2 * k + 1) * 2 + 0];
    a1 += v.x * Wcs[128 + (2 * k) * 2 + 1] + v.y * Wcs[128 + (2 * k + 1) * 2 + 1];
  }
  out[(size_t)e * 2 + 0] = 1.0f / (1.0f + __expf(-a0));
  out[(size_t)e * 2 + 1] = 1.0f / (1.0f + __expf(-a1));
}

extern "C" void kernel_launch(void* const* d_in, const int* in_sizes, int n_in,
                              void* d_out, int out_size, void* d_ws,
                              size_t ws_size, hipStream_t stream) {
  const float* x   = (const float*)d_in[0];
  const float* W0p = (const float*)d_in[1];
  const float* b0p = (const float*)d_in[2];
  const float* W0n = (const float*)d_in[3];
  const float* b0n = (const float*)d_in[4];
  const float* W1p = (const float*)d_in[5];
  const float* b1p = (const float*)d_in[6];
  const float* W1n = (const float*)d_in[7];
  const float* b1n = (const float*)d_in[8];
  const float* Wc  = (const float*)d_in[9];
  const float* bc  = (const float*)d_in[10];
  const int* sp = (const int*)d_in[11];
  const int* dp = (const int*)d_in[12];
  const int* sn = (const int*)d_in[13];
  const int* dn = (const int*)d_in[14];
  const int* ei = (const int*)d_in[15];

  // workspace layout (~49.7 MB)
  float* csrc_p = (float*)d_ws;                       // N
  float* csrc_n = csrc_p + N_NODES;                   // N
  int* offs_p = (int*)(csrc_n + N_NODES);             // N
  int* deg_p  = offs_p + N_NODES;                     // N
  int* offs_n = deg_p + N_NODES;                      // N
  int* deg_n  = offs_n + N_NODES;                     // N
  int* gcur   = deg_n + N_NODES;                      // 2*NBUCK (+ pad to 16B)
  unsigned* bin_d = (unsigned*)(gcur + 2 * NBUCK + 2);       // NBUCK*BCAP
  unsigned* bin_s = bin_d + (size_t)NBUCK * BCAP;            // NBUCK*BCAP
  int* srclist = (int*)(bin_s + (size_t)NBUCK * BCAP);       // NBUCK*BCAP
  __half* A = (__half*)(srclist + (size_t)NBUCK * BCAP);     // N*64 fp16
  __half* B = A + (size_t)N_NODES * 64;                      // N*64 fp16
  __half* zh = A;  // alias: A is dead after gather_mid(neg)

  float* z     = (float*)d_out;                   // N*64 fp32
  float* probs = z + (size_t)N_NODES * 64;        // E_Q*2 fp32

  int* gcur_d = gcur;
  int* gcur_s = gcur + NBUCK;

  const int gemmGrid = (N_NODES + 255) / 256;
  const int aggGrid  = (N_NODES * 64 + 255) / 256;

  // ---- POS relation ----
  hipMemsetAsync(gcur, 0, 2 * NBUCK * sizeof(int), stream);
  bin_edges<<<P1_BLOCKS, 256, 0, stream>>>(sp, dp, gcur_d, gcur_s, bin_d, bin_s);
  build_csr<<<NBUCK, 256, 0, stream>>>(bin_d, gcur_d, offs_p, deg_p, srclist);
  src_hist<<<NBUCK, 256, 0, stream>>>(bin_s, gcur_s, csrc_p);
  gemm_in_h<<<gemmGrid, 256, 0, stream>>>(x, W0p, csrc_p, A);
  gather_mid<<<aggGrid, 256, 0, stream>>>(A, offs_p, deg_p, srclist, b0p,
                                          csrc_p, W1p, B);
  gather_fin<0><<<aggGrid, 256, 0, stream>>>(B, offs_p, deg_p, srclist, b1p, z,
                                             zh);

  // ---- NEG relation ---- (bin_d/bin_s/srclist reused; pos consumers done)
  hipMemsetAsync(gcur, 0, 2 * NBUCK * sizeof(int), stream);
  bin_edges<<<P1_BLOCKS, 256, 0, stream>>>(sn, dn, gcur_d, gcur_s, bin_d, bin_s);
  build_csr<<<NBUCK, 256, 0, stream>>>(bin_d, gcur_d, offs_n, deg_n, srclist);
  src_hist<<<NBUCK, 256, 0, stream>>>(bin_s, gcur_s, csrc_n);
  gemm_in_h<<<gemmGrid, 256, 0, stream>>>(x, W0n, csrc_n, A);
  gather_mid<<<aggGrid, 256, 0, stream>>>(A, offs_n, deg_n, srclist, b0n,
                                          csrc_n, W1n, B);
  gather_fin<1><<<aggGrid, 256, 0, stream>>>(B, offs_n, deg_n, srclist, b1n, z,
                                             zh);

  // ---- classifier (fp16 z rows) ----
  classify_kernel<<<(E_QQ + 255) / 256, 256, 0, stream>>>(zh, ei, Wc, bc, probs);
}

// Round 6
// 668.380 us; speedup vs baseline: 3.2661x; 1.3710x over previous
//
#include <hip/hip_runtime.h>
#include <hip/hip_fp16.h>
#include <math.h>

#define N_NODES 100000
#define DIM 64
#define E_REL 1600000
#define E_QQ 1000000

#define NBUCK 196      // ceil(100000 / 512) node buckets of 512
#define BCAP 9216      // capacity per bucket; expected 8192, +11 sigma slack
#define CHUNK_E 8192   // edges per phase-1 block
#define P1_BLOCKS ((E_REL + CHUNK_E - 1) / CHUNK_E)  // 196

// ---------------------------------------------------------------------------
// Phase 1: bin edges by dst-bucket (packed (dlocal<<17)|src) and by src-bucket
// (raw src). Per-block LDS counts; ~2*NBUCK global atomics per block reserve
// space; placement via LDS cursors + plain (write-back) stores.
// ---------------------------------------------------------------------------
__global__ __launch_bounds__(256) void bin_edges(
    const int* __restrict__ src, const int* __restrict__ dst,
    int* __restrict__ gcur_d, int* __restrict__ gcur_s,
    unsigned* __restrict__ bin_d, unsigned* __restrict__ bin_s) {
  __shared__ int cd[NBUCK];
  __shared__ int cs[NBUCK];
  int t = threadIdx.x;
  for (int i = t; i < NBUCK; i += 256) { cd[i] = 0; cs[i] = 0; }
  __syncthreads();
  int e0 = blockIdx.x * CHUNK_E;
  int e1 = e0 + CHUNK_E;
  if (e1 > E_REL) e1 = E_REL;
  for (int e = e0 + t; e < e1; e += 256) {
    atomicAdd(&cd[dst[e] >> 9], 1);
    atomicAdd(&cs[src[e] >> 9], 1);
  }
  __syncthreads();
  for (int i = t; i < NBUCK; i += 256) {
    cd[i] = atomicAdd(&gcur_d[i], cd[i]);
    cs[i] = atomicAdd(&gcur_s[i], cs[i]);
  }
  __syncthreads();
  for (int e = e0 + t; e < e1; e += 256) {
    int s = src[e];
    int d = dst[e];
    int bd = d >> 9;
    int bs = s >> 9;
    int pd = atomicAdd(&cd[bd], 1);
    int ps = atomicAdd(&cs[bs], 1);
    if ((unsigned)pd < BCAP)
      bin_d[(size_t)bd * BCAP + pd] = (unsigned)(((d & 511) << 17) | s);
    if ((unsigned)ps < BCAP)
      bin_s[(size_t)bs * BCAP + ps] = (unsigned)s;
  }
}

// ---------------------------------------------------------------------------
// Phase 2 (dst): one block per bucket (512 nodes). LDS node histogram ->
// scan -> compact per-node src lists + offs/deg.
// ---------------------------------------------------------------------------
__global__ __launch_bounds__(256) void build_csr(
    const unsigned* __restrict__ bin_d, const int* __restrict__ gcur_d,
    int* __restrict__ offs, int* __restrict__ degv, int* __restrict__ srclist) {
  __shared__ int cnt[512];
  __shared__ int off0[512];
  __shared__ int curv[512];
  __shared__ int ls[256];
  int b = blockIdx.x, t = threadIdx.x;
  cnt[t] = 0;
  cnt[t + 256] = 0;
  __syncthreads();
  int n = gcur_d[b];
  if (n > BCAP) n = BCAP;
  const unsigned* be = bin_d + (size_t)b * BCAP;
  for (int i = t; i < n; i += 256) atomicAdd(&cnt[be[i] >> 17], 1);
  __syncthreads();
  int c0 = cnt[2 * t], c1 = cnt[2 * t + 1];
  ls[t] = c0 + c1;
  __syncthreads();
  for (int off = 1; off < 256; off <<= 1) {
    int v = (t >= off) ? ls[t - off] : 0;
    __syncthreads();
    ls[t] += v;
    __syncthreads();
  }
  int base = ls[t] - (c0 + c1);
  off0[2 * t] = base;
  off0[2 * t + 1] = base + c0;
  curv[2 * t] = base;
  curv[2 * t + 1] = base + c0;
  __syncthreads();
  for (int i = t; i < n; i += 256) {
    unsigned p = be[i];
    int dl = p >> 17;
    int pos = atomicAdd(&curv[dl], 1);
    srclist[(size_t)b * BCAP + pos] = (int)(p & 0x1FFFF);
  }
  __syncthreads();
  int node0 = b << 9;
  for (int i = t; i < 512; i += 256) {
    int node = node0 + i;
    if (node < N_NODES) {
      offs[node] = b * BCAP + off0[i];
      degv[node] = cnt[i];
    }
  }
}

// ---------------------------------------------------------------------------
// Phase 2 (src): LDS histogram per bucket -> csrc = rsqrt(outdeg) (or 0)
// ---------------------------------------------------------------------------
__global__ __launch_bounds__(256) void src_hist(
    const unsigned* __restrict__ bin_s, const int* __restrict__ gcur_s,
    float* __restrict__ csrc) {
  __shared__ int h[512];
  int b = blockIdx.x, t = threadIdx.x;
  h[t] = 0;
  h[t + 256] = 0;
  __syncthreads();
  int n = gcur_s[b];
  if (n > BCAP) n = BCAP;
  const unsigned* be = bin_s + (size_t)b * BCAP;
  for (int i = t; i < n; i += 256) atomicAdd(&h[be[i] & 511], 1);
  __syncthreads();
  int node0 = b << 9;
  for (int i = t; i < 512; i += 256) {
    int node = node0 + i;
    if (node < N_NODES) {
      int d = h[i];
      csrc[node] = d > 0 ? rsqrtf((float)d) : 0.0f;
    }
  }
}

__device__ inline unsigned pack_h2(float a, float b) {
  __half2 h = __floats2half2_rn(a, b);
  return *reinterpret_cast<unsigned*>(&h);
}

// ---------------------------------------------------------------------------
// Y[row] = fp16( csrc[row] * (X[row] @ W) )   thread-per-row, W in LDS
// ---------------------------------------------------------------------------
__global__ __launch_bounds__(256) void gemm_in_h(
    const float* __restrict__ X, const float* __restrict__ W,
    const float* __restrict__ csrc, __half* __restrict__ Y) {
  __shared__ float Ws[64 * 64];
  for (int t = threadIdx.x; t < 64 * 64; t += 256) Ws[t] = W[t];
  __syncthreads();
  int row = blockIdx.x * 256 + threadIdx.x;
  if (row >= N_NODES) return;
  const float4* xr = (const float4*)(X + (size_t)row * 64);
  float acc[64];
#pragma unroll
  for (int j = 0; j < 64; j++) acc[j] = 0.0f;
#pragma unroll
  for (int k4 = 0; k4 < 16; k4++) {
    float4 xv = xr[k4];
    const float* w0 = &Ws[(k4 * 4 + 0) * 64];
    const float* w1 = &Ws[(k4 * 4 + 1) * 64];
    const float* w2 = &Ws[(k4 * 4 + 2) * 64];
    const float* w3 = &Ws[(k4 * 4 + 3) * 64];
#pragma unroll
    for (int j = 0; j < 64; j++)
      acc[j] += xv.x * w0[j] + xv.y * w1[j] + xv.z * w2[j] + xv.w * w3[j];
  }
  float s = csrc[row];
  uint4* yr = (uint4*)(Y + (size_t)row * 64);
#pragma unroll
  for (int j8 = 0; j8 < 8; j8++) {
    uint4 u;
    u.x = pack_h2(s * acc[j8 * 8 + 0], s * acc[j8 * 8 + 1]);
    u.y = pack_h2(s * acc[j8 * 8 + 2], s * acc[j8 * 8 + 3]);
    u.z = pack_h2(s * acc[j8 * 8 + 4], s * acc[j8 * 8 + 5]);
    u.w = pack_h2(s * acc[j8 * 8 + 6], s * acc[j8 * 8 + 7]);
    yr[j8] = u;
  }
}

// ---------------------------------------------------------------------------
// Quad-edge aggregation core: wave = 1 node, lanes split 4 (edge slot q) x
// 16 (feature quad l). Each lane loads uint2 = 4 fp16 feats of row s_q ->
// 4 rows in flight per load instruction. Result: every lane holds the
// complete float4 sum for features 4l..4l+3 after the xor-reduce.
// ---------------------------------------------------------------------------
__device__ inline float4 agg_quad(const __half* __restrict__ Y, int beg,
                                  int deg, const int* __restrict__ srclist,
                                  int lane, int l, int q) {
  float4 acc = make_float4(0.f, 0.f, 0.f, 0.f);
  for (int base = 0; base < deg; base += 64) {
    int chunk = deg - base;
    if (chunk > 64) chunk = 64;
    int sv = (base + lane < deg) ? srclist[beg + base + lane] : 0;
    int nq = chunk & ~3;
    for (int j = 0; j < nq; j += 4) {
      int s = __shfl(sv, j + q);
      uint2 u = *(const uint2*)(Y + (size_t)s * 64 + 4 * l);
      __half2 h0 = *reinterpret_cast<__half2*>(&u.x);
      __half2 h1 = *reinterpret_cast<__half2*>(&u.y);
      float2 f0 = __half22float2(h0);
      float2 f1 = __half22float2(h1);
      acc.x += f0.x; acc.y += f0.y; acc.z += f1.x; acc.w += f1.y;
    }
    if (nq < chunk) {
      int j = nq + q;  // <= 63 always
      int s = __shfl(sv, j);
      if (j < chunk) {
        uint2 u = *(const uint2*)(Y + (size_t)s * 64 + 4 * l);
        __half2 h0 = *reinterpret_cast<__half2*>(&u.x);
        __half2 h1 = *reinterpret_cast<__half2*>(&u.y);
        float2 f0 = __half22float2(h0);
        float2 f1 = __half22float2(h1);
        acc.x += f0.x; acc.y += f0.y; acc.z += f1.x; acc.w += f1.y;
      }
    }
  }
  acc.x += __shfl_xor(acc.x, 16); acc.y += __shfl_xor(acc.y, 16);
  acc.z += __shfl_xor(acc.z, 16); acc.w += __shfl_xor(acc.w, 16);
  acc.x += __shfl_xor(acc.x, 32); acc.y += __shfl_xor(acc.y, 32);
  acc.z += __shfl_xor(acc.z, 32); acc.w += __shfl_xor(acc.w, 32);
  return acc;
}

// ---------------------------------------------------------------------------
// Fused: conv1 aggregation + epilogue + conv2 input GEMM (h row via LDS).
// ---------------------------------------------------------------------------
__global__ __launch_bounds__(256) void gather_mid(
    const __half* __restrict__ Y, const int* __restrict__ offs,
    const int* __restrict__ degv, const int* __restrict__ srclist,
    const float* __restrict__ b0, const float* __restrict__ csrc,
    const float* __restrict__ W1, __half* __restrict__ Y2) {
  __shared__ float Ws[64 * 64];
  __shared__ float hs[4][64];
  for (int t = threadIdx.x; t < 64 * 64; t += 256) Ws[t] = W1[t];
  __syncthreads();
  int wid = (blockIdx.x * 256 + threadIdx.x) >> 6;
  int lane = threadIdx.x & 63;
  int wslot = threadIdx.x >> 6;
  if (wid >= N_NODES) return;
  int l = lane & 15, q = lane >> 4;
  int beg = offs[wid];
  int deg = degv[wid];
  float4 acc = agg_quad(Y, beg, deg, srclist, lane, l, q);
  float cd = deg > 0 ? rsqrtf((float)deg) : 0.0f;
  float4 bv = ((const float4*)b0)[l];
  float4 h;
  h.x = fmaxf(acc.x * cd + bv.x, 0.0f);
  h.y = fmaxf(acc.y * cd + bv.y, 0.0f);
  h.z = fmaxf(acc.z * cd + bv.z, 0.0f);
  h.w = fmaxf(acc.w * cd + bv.w, 0.0f);
  if (lane < 16) *((float4*)&hs[wslot][4 * l]) = h;
  // same-wave LDS RAW: in-order DS pipe, no barrier needed
  float acc2 = 0.0f;
#pragma unroll
  for (int k4 = 0; k4 < 16; k4++) {
    float4 hv = *((const float4*)&hs[wslot][4 * k4]);
    acc2 += hv.x * Ws[(4 * k4 + 0) * 64 + lane] +
            hv.y * Ws[(4 * k4 + 1) * 64 + lane] +
            hv.z * Ws[(4 * k4 + 2) * 64 + lane] +
            hv.w * Ws[(4 * k4 + 3) * 64 + lane];
  }
  Y2[(size_t)wid * 64 + lane] = __float2half(csrc[wid] * acc2);
}

// ---------------------------------------------------------------------------
// Final aggregation + epilogue into z (fp32 output).
// MODE 0: z = relu(...)
// MODE 1: z -= relu(...), and emit uv[node] = {z.Wc_top(2), z.Wc_bot(2)}
// ---------------------------------------------------------------------------
template <int MODE>
__global__ __launch_bounds__(256) void gather_fin(
    const __half* __restrict__ Y2, const int* __restrict__ offs,
    const int* __restrict__ degv, const int* __restrict__ srclist,
    const float* __restrict__ b1, float* __restrict__ z,
    float* __restrict__ uv, const float* __restrict__ Wc) {
  __shared__ float Wcs[256];
  if (MODE == 1) {
    Wcs[threadIdx.x] = Wc[threadIdx.x];
    __syncthreads();
  }
  int wid = (blockIdx.x * 256 + threadIdx.x) >> 6;
  int lane = threadIdx.x & 63;
  if (wid >= N_NODES) return;
  int l = lane & 15, q = lane >> 4;
  int beg = offs[wid];
  int deg = degv[wid];
  float4 acc = agg_quad(Y2, beg, deg, srclist, lane, l, q);
  float cd = deg > 0 ? rsqrtf((float)deg) : 0.0f;
  float4 bv = ((const float4*)b1)[l];
  float4 v;
  v.x = fmaxf(acc.x * cd + bv.x, 0.0f);
  v.y = fmaxf(acc.y * cd + bv.y, 0.0f);
  v.z = fmaxf(acc.z * cd + bv.z, 0.0f);
  v.w = fmaxf(acc.w * cd + bv.w, 0.0f);
  float* zrow = z + (size_t)wid * 64 + 4 * l;
  if (MODE == 0) {
    if (lane < 16) *((float4*)zrow) = v;
  } else {
    float4 zo = *((const float4*)zrow);
    float4 r;
    r.x = zo.x - v.x; r.y = zo.y - v.y; r.z = zo.z - v.z; r.w = zo.w - v.w;
    if (lane < 16) *((float4*)zrow) = r;
    // uv partials: rows 4l..4l+3 (top) and 64+4l.. (bottom), cols 0/1
    float pu0 = r.x * Wcs[(4 * l + 0) * 2 + 0] + r.y * Wcs[(4 * l + 1) * 2 + 0] +
                r.z * Wcs[(4 * l + 2) * 2 + 0] + r.w * Wcs[(4 * l + 3) * 2 + 0];
    float pu1 = r.x * Wcs[(4 * l + 0) * 2 + 1] + r.y * Wcs[(4 * l + 1) * 2 + 1] +
                r.z * Wcs[(4 * l + 2) * 2 + 1] + r.w * Wcs[(4 * l + 3) * 2 + 1];
    float pv0 = r.x * Wcs[(64 + 4 * l + 0) * 2 + 0] + r.y * Wcs[(64 + 4 * l + 1) * 2 + 0] +
                r.z * Wcs[(64 + 4 * l + 2) * 2 + 0] + r.w * Wcs[(64 + 4 * l + 3) * 2 + 0];
    float pv1 = r.x * Wcs[(64 + 4 * l + 0) * 2 + 1] + r.y * Wcs[(64 + 4 * l + 1) * 2 + 1] +
                r.z * Wcs[(64 + 4 * l + 2) * 2 + 1] + r.w * Wcs[(64 + 4 * l + 3) * 2 + 1];
#pragma unroll
    for (int o = 1; o < 16; o <<= 1) {
      pu0 += __shfl_xor(pu0, o);
      pu1 += __shfl_xor(pu1, o);
      pv0 += __shfl_xor(pv0, o);
      pv1 += __shfl_xor(pv1, o);
    }
    if (lane == 0) {
      float4 o4 = make_float4(pu0, pu1, pv0, pv1);
      *((float4*)(uv + (size_t)wid * 4)) = o4;
    }
  }
}

// ---------------------------------------------------------------------------
// probs[e] = sigmoid(u(s) + v(d) + bc)  — factorized classifier, 16 B loads
// from the 1.6 MB L2-resident uv table.
// ---------------------------------------------------------------------------
__global__ __launch_bounds__(256) void classify_kernel(
    const float* __restrict__ uv, const int* __restrict__ ei,
    const float* __restrict__ bc, float* __restrict__ out) {
  int e = blockIdx.x * 256 + threadIdx.x;
  if (e >= E_QQ) return;
  int s = ei[e];
  int d = ei[E_QQ + e];
  float4 us = *((const float4*)(uv + (size_t)s * 4));
  float4 vd = *((const float4*)(uv + (size_t)d * 4));
  float l0 = us.x + vd.z + bc[0];
  float l1 = us.y + vd.w + bc[1];
  float2 o;
  o.x = 1.0f / (1.0f + __expf(-l0));
  o.y = 1.0f / (1.0f + __expf(-l1));
  *((float2*)(out + (size_t)e * 2)) = o;
}

extern "C" void kernel_launch(void* const* d_in, const int* in_sizes, int n_in,
                              void* d_out, int out_size, void* d_ws,
                              size_t ws_size, hipStream_t stream) {
  const float* x   = (const float*)d_in[0];
  const float* W0p = (const float*)d_in[1];
  const float* b0p = (const float*)d_in[2];
  const float* W0n = (const float*)d_in[3];
  const float* b0n = (const float*)d_in[4];
  const float* W1p = (const float*)d_in[5];
  const float* b1p = (const float*)d_in[6];
  const float* W1n = (const float*)d_in[7];
  const float* b1n = (const float*)d_in[8];
  const float* Wc  = (const float*)d_in[9];
  const float* bc  = (const float*)d_in[10];
  const int* sp = (const int*)d_in[11];
  const int* dp = (const int*)d_in[12];
  const int* sn = (const int*)d_in[13];
  const int* dn = (const int*)d_in[14];
  const int* ei = (const int*)d_in[15];

  // workspace layout (~53 MB)
  float* csrc_p = (float*)d_ws;                       // N
  float* csrc_n = csrc_p + N_NODES;                   // N
  int* offs_p = (int*)(csrc_n + N_NODES);             // N
  int* deg_p  = offs_p + N_NODES;                     // N
  int* offs_n = deg_p + N_NODES;                      // N
  int* deg_n  = offs_n + N_NODES;                     // N
  float* uv   = (float*)(deg_n + N_NODES);            // 4N
  int* gcur   = (int*)(uv + 4 * N_NODES);             // 2*NBUCK (+pad)
  unsigned* bin_d = (unsigned*)(gcur + 2 * NBUCK + 2);       // NBUCK*BCAP
  unsigned* bin_s = bin_d + (size_t)NBUCK * BCAP;            // NBUCK*BCAP
  int* srclist = (int*)(bin_s + (size_t)NBUCK * BCAP);       // NBUCK*BCAP
  __half* A = (__half*)(srclist + (size_t)NBUCK * BCAP);     // N*64 fp16
  __half* B = A + (size_t)N_NODES * 64;                      // N*64 fp16

  float* z     = (float*)d_out;                   // N*64 fp32
  float* probs = z + (size_t)N_NODES * 64;        // E_Q*2 fp32

  int* gcur_d = gcur;
  int* gcur_s = gcur + NBUCK;

  const int gemmGrid = (N_NODES + 255) / 256;
  const int aggGrid  = (N_NODES * 64 + 255) / 256;

  // ---- POS relation ----
  hipMemsetAsync(gcur, 0, 2 * NBUCK * sizeof(int), stream);
  bin_edges<<<P1_BLOCKS, 256, 0, stream>>>(sp, dp, gcur_d, gcur_s, bin_d, bin_s);
  build_csr<<<NBUCK, 256, 0, stream>>>(bin_d, gcur_d, offs_p, deg_p, srclist);
  src_hist<<<NBUCK, 256, 0, stream>>>(bin_s, gcur_s, csrc_p);
  gemm_in_h<<<gemmGrid, 256, 0, stream>>>(x, W0p, csrc_p, A);
  gather_mid<<<aggGrid, 256, 0, stream>>>(A, offs_p, deg_p, srclist, b0p,
                                          csrc_p, W1p, B);
  gather_fin<0><<<aggGrid, 256, 0, stream>>>(B, offs_p, deg_p, srclist, b1p, z,
                                             uv, Wc);

  // ---- NEG relation ---- (bins/srclist reused; pos consumers done)
  hipMemsetAsync(gcur, 0, 2 * NBUCK * sizeof(int), stream);
  bin_edges<<<P1_BLOCKS, 256, 0, stream>>>(sn, dn, gcur_d, gcur_s, bin_d, bin_s);
  build_csr<<<NBUCK, 256, 0, stream>>>(bin_d, gcur_d, offs_n, deg_n, srclist);
  src_hist<<<NBUCK, 256, 0, stream>>>(bin_s, gcur_s, csrc_n);
  gemm_in_h<<<gemmGrid, 256, 0, stream>>>(x, W0n, csrc_n, A);
  gather_mid<<<aggGrid, 256, 0, stream>>>(A, offs_n, deg_n, srclist, b0n,
                                          csrc_n, W1n, B);
  gather_fin<1><<<aggGrid, 256, 0, stream>>>(B, offs_n, deg_n, srclist, b1n, z,
                                             uv, Wc);

  // ---- classifier (factorized) ----
  classify_kernel<<<(E_QQ + 255) / 256, 256, 0, stream>>>(uv, ei, bc, probs);
}

// Round 7
// 627.744 us; speedup vs baseline: 3.4776x; 1.0647x over previous
//
#include <hip/hip_runtime.h>
#include <hip/hip_fp16.h>
#include <math.h>

#define N_NODES 100000
#define DIM 64
#define E_REL 1600000
#define E_QQ 1000000

#define NBUCK 196      // ceil(100000 / 512) node buckets of 512
#define BCAP 9216      // capacity per bucket; expected 8192, +11 sigma slack
#define CHUNK_E 8192   // edges per phase-1 block
#define P1_BLOCKS ((E_REL + CHUNK_E - 1) / CHUNK_E)  // 196

// ---------------------------------------------------------------------------
// Phase 1: bin edges by dst-bucket (packed (dlocal<<17)|src) and by src-bucket
// (raw src). Per-block LDS counts; ~2*NBUCK global atomics per block reserve
// space; placement via LDS cursors + plain (write-back) stores.
// ---------------------------------------------------------------------------
__global__ __launch_bounds__(256) void bin_edges(
    const int* __restrict__ src, const int* __restrict__ dst,
    int* __restrict__ gcur_d, int* __restrict__ gcur_s,
    unsigned* __restrict__ bin_d, unsigned* __restrict__ bin_s) {
  __shared__ int cd[NBUCK];
  __shared__ int cs[NBUCK];
  int t = threadIdx.x;
  for (int i = t; i < NBUCK; i += 256) { cd[i] = 0; cs[i] = 0; }
  __syncthreads();
  int e0 = blockIdx.x * CHUNK_E;
  int e1 = e0 + CHUNK_E;
  if (e1 > E_REL) e1 = E_REL;
  for (int e = e0 + t; e < e1; e += 256) {
    atomicAdd(&cd[dst[e] >> 9], 1);
    atomicAdd(&cs[src[e] >> 9], 1);
  }
  __syncthreads();
  for (int i = t; i < NBUCK; i += 256) {
    cd[i] = atomicAdd(&gcur_d[i], cd[i]);
    cs[i] = atomicAdd(&gcur_s[i], cs[i]);
  }
  __syncthreads();
  for (int e = e0 + t; e < e1; e += 256) {
    int s = src[e];
    int d = dst[e];
    int bd = d >> 9;
    int bs = s >> 9;
    int pd = atomicAdd(&cd[bd], 1);
    int ps = atomicAdd(&cs[bs], 1);
    if ((unsigned)pd < BCAP)
      bin_d[(size_t)bd * BCAP + pd] = (unsigned)(((d & 511) << 17) | s);
    if ((unsigned)ps < BCAP)
      bin_s[(size_t)bs * BCAP + ps] = (unsigned)s;
  }
}

// ---------------------------------------------------------------------------
// Phase 2 fused: blocks 0..NBUCK-1 build the dst-CSR (histogram -> scan ->
// compact per-node src lists + offs/deg); blocks NBUCK..2*NBUCK-1 build the
// src-degree norm table csrc = rsqrt(outdeg).
// ---------------------------------------------------------------------------
__global__ __launch_bounds__(256) void build_tables(
    const unsigned* __restrict__ bin_d, const int* __restrict__ gcur_d,
    const unsigned* __restrict__ bin_s, const int* __restrict__ gcur_s,
    int* __restrict__ offs, int* __restrict__ degv, int* __restrict__ srclist,
    float* __restrict__ csrc) {
  __shared__ int cnt[512];
  __shared__ int off0[512];
  __shared__ int curv[512];
  __shared__ int ls[256];
  int t = threadIdx.x;
  if (blockIdx.x >= NBUCK) {
    // ---- src histogram -> csrc ----
    int b = blockIdx.x - NBUCK;
    cnt[t] = 0;
    cnt[t + 256] = 0;
    __syncthreads();
    int n = gcur_s[b];
    if (n > BCAP) n = BCAP;
    const unsigned* be = bin_s + (size_t)b * BCAP;
    for (int i = t; i < n; i += 256) atomicAdd(&cnt[be[i] & 511], 1);
    __syncthreads();
    int node0 = b << 9;
    for (int i = t; i < 512; i += 256) {
      int node = node0 + i;
      if (node < N_NODES) {
        int d = cnt[i];
        csrc[node] = d > 0 ? rsqrtf((float)d) : 0.0f;
      }
    }
    return;
  }
  // ---- dst CSR ----
  int b = blockIdx.x;
  cnt[t] = 0;
  cnt[t + 256] = 0;
  __syncthreads();
  int n = gcur_d[b];
  if (n > BCAP) n = BCAP;
  const unsigned* be = bin_d + (size_t)b * BCAP;
  for (int i = t; i < n; i += 256) atomicAdd(&cnt[be[i] >> 17], 1);
  __syncthreads();
  int c0 = cnt[2 * t], c1 = cnt[2 * t + 1];
  ls[t] = c0 + c1;
  __syncthreads();
  for (int off = 1; off < 256; off <<= 1) {
    int v = (t >= off) ? ls[t - off] : 0;
    __syncthreads();
    ls[t] += v;
    __syncthreads();
  }
  int base = ls[t] - (c0 + c1);
  off0[2 * t] = base;
  off0[2 * t + 1] = base + c0;
  curv[2 * t] = base;
  curv[2 * t + 1] = base + c0;
  __syncthreads();
  for (int i = t; i < n; i += 256) {
    unsigned p = be[i];
    int dl = p >> 17;
    int pos = atomicAdd(&curv[dl], 1);
    srclist[(size_t)b * BCAP + pos] = (int)(p & 0x1FFFF);
  }
  __syncthreads();
  int node0 = b << 9;
  for (int i = t; i < 512; i += 256) {
    int node = node0 + i;
    if (node < N_NODES) {
      offs[node] = b * BCAP + off0[i];
      degv[node] = cnt[i];
    }
  }
}

__device__ inline unsigned pack_h2(float a, float b) {
  __half2 h = __floats2half2_rn(a, b);
  return *reinterpret_cast<unsigned*>(&h);
}

// ---------------------------------------------------------------------------
// Y[row] = fp16( csrc[row] * (X[row] @ W) )   thread-per-row, W in LDS
// ---------------------------------------------------------------------------
__global__ __launch_bounds__(256) void gemm_in_h(
    const float* __restrict__ X, const float* __restrict__ W,
    const float* __restrict__ csrc, __half* __restrict__ Y) {
  __shared__ float Ws[64 * 64];
  for (int t = threadIdx.x; t < 64 * 64; t += 256) Ws[t] = W[t];
  __syncthreads();
  int row = blockIdx.x * 256 + threadIdx.x;
  if (row >= N_NODES) return;
  const float4* xr = (const float4*)(X + (size_t)row * 64);
  float acc[64];
#pragma unroll
  for (int j = 0; j < 64; j++) acc[j] = 0.0f;
#pragma unroll
  for (int k4 = 0; k4 < 16; k4++) {
    float4 xv = xr[k4];
    const float* w0 = &Ws[(k4 * 4 + 0) * 64];
    const float* w1 = &Ws[(k4 * 4 + 1) * 64];
    const float* w2 = &Ws[(k4 * 4 + 2) * 64];
    const float* w3 = &Ws[(k4 * 4 + 3) * 64];
#pragma unroll
    for (int j = 0; j < 64; j++)
      acc[j] += xv.x * w0[j] + xv.y * w1[j] + xv.z * w2[j] + xv.w * w3[j];
  }
  float s = csrc[row];
  uint4* yr = (uint4*)(Y + (size_t)row * 64);
#pragma unroll
  for (int j8 = 0; j8 < 8; j8++) {
    uint4 u;
    u.x = pack_h2(s * acc[j8 * 8 + 0], s * acc[j8 * 8 + 1]);
    u.y = pack_h2(s * acc[j8 * 8 + 2], s * acc[j8 * 8 + 3]);
    u.z = pack_h2(s * acc[j8 * 8 + 4], s * acc[j8 * 8 + 5]);
    u.w = pack_h2(s * acc[j8 * 8 + 6], s * acc[j8 * 8 + 7]);
    yr[j8] = u;
  }
}

// ---------------------------------------------------------------------------
// Quad-edge aggregation core, unrolled x2: wave = 1 node, lanes split
// 4 (edge slot q) x 16 (feature quad l). Per iteration each lane issues TWO
// independent uint2 loads (8 edges in flight per wave instruction pair) into
// two separate accumulators -> MLP 8 rows/wave, no add-chain dependency.
// ---------------------------------------------------------------------------
__device__ inline float4 agg_quad(const __half* __restrict__ Y, int beg,
                                  int deg, const int* __restrict__ srclist,
                                  int lane, int l, int q) {
  float4 a0 = make_float4(0.f, 0.f, 0.f, 0.f);
  float4 a1 = make_float4(0.f, 0.f, 0.f, 0.f);
  const __half* Yl = Y + 4 * l;
  for (int base = 0; base < deg; base += 64) {
    int chunk = deg - base;
    if (chunk > 64) chunk = 64;
    int sv = (base + lane < deg) ? srclist[beg + base + lane] : 0;
    int nq8 = chunk & ~7;
    for (int j = 0; j < nq8; j += 8) {
      int s0 = __shfl(sv, j + q);
      int s1 = __shfl(sv, j + 4 + q);
      uint2 u0 = *(const uint2*)(Yl + (size_t)s0 * 64);
      uint2 u1 = *(const uint2*)(Yl + (size_t)s1 * 64);
      float2 f;
      f = __half22float2(*reinterpret_cast<__half2*>(&u0.x));
      a0.x += f.x; a0.y += f.y;
      f = __half22float2(*reinterpret_cast<__half2*>(&u0.y));
      a0.z += f.x; a0.w += f.y;
      f = __half22float2(*reinterpret_cast<__half2*>(&u1.x));
      a1.x += f.x; a1.y += f.y;
      f = __half22float2(*reinterpret_cast<__half2*>(&u1.y));
      a1.z += f.x; a1.w += f.y;
    }
    // remainder (up to 7 edges): two masked quad steps
    int j0 = nq8 + q;
    int j1 = nq8 + 4 + q;
    int s0 = __shfl(sv, j0 & 63);
    int s1 = __shfl(sv, j1 & 63);
    if (j0 < chunk) {
      uint2 u = *(const uint2*)(Yl + (size_t)s0 * 64);
      float2 f;
      f = __half22float2(*reinterpret_cast<__half2*>(&u.x));
      a0.x += f.x; a0.y += f.y;
      f = __half22float2(*reinterpret_cast<__half2*>(&u.y));
      a0.z += f.x; a0.w += f.y;
    }
    if (j1 < chunk) {
      uint2 u = *(const uint2*)(Yl + (size_t)s1 * 64);
      float2 f;
      f = __half22float2(*reinterpret_cast<__half2*>(&u.x));
      a1.x += f.x; a1.y += f.y;
      f = __half22float2(*reinterpret_cast<__half2*>(&u.y));
      a1.z += f.x; a1.w += f.y;
    }
  }
  a0.x += a1.x; a0.y += a1.y; a0.z += a1.z; a0.w += a1.w;
  a0.x += __shfl_xor(a0.x, 16); a0.y += __shfl_xor(a0.y, 16);
  a0.z += __shfl_xor(a0.z, 16); a0.w += __shfl_xor(a0.w, 16);
  a0.x += __shfl_xor(a0.x, 32); a0.y += __shfl_xor(a0.y, 32);
  a0.z += __shfl_xor(a0.z, 32); a0.w += __shfl_xor(a0.w, 32);
  return a0;
}

// ---------------------------------------------------------------------------
// Fused: conv1 aggregation + epilogue + conv2 input GEMM (h row via LDS).
// ---------------------------------------------------------------------------
__global__ __launch_bounds__(256) void gather_mid(
    const __half* __restrict__ Y, const int* __restrict__ offs,
    const int* __restrict__ degv, const int* __restrict__ srclist,
    const float* __restrict__ b0, const float* __restrict__ csrc,
    const float* __restrict__ W1, __half* __restrict__ Y2) {
  __shared__ float Ws[64 * 64];
  __shared__ float hs[4][64];
  for (int t = threadIdx.x; t < 64 * 64; t += 256) Ws[t] = W1[t];
  __syncthreads();
  int wid = (blockIdx.x * 256 + threadIdx.x) >> 6;
  int lane = threadIdx.x & 63;
  int wslot = threadIdx.x >> 6;
  if (wid >= N_NODES) return;
  int l = lane & 15, q = lane >> 4;
  int beg = offs[wid];
  int deg = degv[wid];
  float4 acc = agg_quad(Y, beg, deg, srclist, lane, l, q);
  float cd = deg > 0 ? rsqrtf((float)deg) : 0.0f;
  float4 bv = ((const float4*)b0)[l];
  float4 h;
  h.x = fmaxf(acc.x * cd + bv.x, 0.0f);
  h.y = fmaxf(acc.y * cd + bv.y, 0.0f);
  h.z = fmaxf(acc.z * cd + bv.z, 0.0f);
  h.w = fmaxf(acc.w * cd + bv.w, 0.0f);
  if (lane < 16) *((float4*)&hs[wslot][4 * l]) = h;
  // same-wave LDS RAW: in-order DS pipe, no barrier needed
  float acc2 = 0.0f;
#pragma unroll
  for (int k4 = 0; k4 < 16; k4++) {
    float4 hv = *((const float4*)&hs[wslot][4 * k4]);
    acc2 += hv.x * Ws[(4 * k4 + 0) * 64 + lane] +
            hv.y * Ws[(4 * k4 + 1) * 64 + lane] +
            hv.z * Ws[(4 * k4 + 2) * 64 + lane] +
            hv.w * Ws[(4 * k4 + 3) * 64 + lane];
  }
  Y2[(size_t)wid * 64 + lane] = __float2half(csrc[wid] * acc2);
}

// ---------------------------------------------------------------------------
// Final aggregation + epilogue into z (fp32 output).
// MODE 0: z = relu(...)
// MODE 1: z -= relu(...), and emit uv[node] = {z.Wc_top(2), z.Wc_bot(2)}
// ---------------------------------------------------------------------------
template <int MODE>
__global__ __launch_bounds__(256) void gather_fin(
    const __half* __restrict__ Y2, const int* __restrict__ offs,
    const int* __restrict__ degv, const int* __restrict__ srclist,
    const float* __restrict__ b1, float* __restrict__ z,
    float* __restrict__ uv, const float* __restrict__ Wc) {
  __shared__ float Wcs[256];
  if (MODE == 1) {
    Wcs[threadIdx.x] = Wc[threadIdx.x];
    __syncthreads();
  }
  int wid = (blockIdx.x * 256 + threadIdx.x) >> 6;
  int lane = threadIdx.x & 63;
  if (wid >= N_NODES) return;
  int l = lane & 15, q = lane >> 4;
  int beg = offs[wid];
  int deg = degv[wid];
  float4 acc = agg_quad(Y2, beg, deg, srclist, lane, l, q);
  float cd = deg > 0 ? rsqrtf((float)deg) : 0.0f;
  float4 bv = ((const float4*)b1)[l];
  float4 v;
  v.x = fmaxf(acc.x * cd + bv.x, 0.0f);
  v.y = fmaxf(acc.y * cd + bv.y, 0.0f);
  v.z = fmaxf(acc.z * cd + bv.z, 0.0f);
  v.w = fmaxf(acc.w * cd + bv.w, 0.0f);
  float* zrow = z + (size_t)wid * 64 + 4 * l;
  if (MODE == 0) {
    if (lane < 16) *((float4*)zrow) = v;
  } else {
    float4 zo = *((const float4*)zrow);
    float4 r;
    r.x = zo.x - v.x; r.y = zo.y - v.y; r.z = zo.z - v.z; r.w = zo.w - v.w;
    if (lane < 16) *((float4*)zrow) = r;
    float pu0 = r.x * Wcs[(4 * l + 0) * 2 + 0] + r.y * Wcs[(4 * l + 1) * 2 + 0] +
                r.z * Wcs[(4 * l + 2) * 2 + 0] + r.w * Wcs[(4 * l + 3) * 2 + 0];
    float pu1 = r.x * Wcs[(4 * l + 0) * 2 + 1] + r.y * Wcs[(4 * l + 1) * 2 + 1] +
                r.z * Wcs[(4 * l + 2) * 2 + 1] + r.w * Wcs[(4 * l + 3) * 2 + 1];
    float pv0 = r.x * Wcs[(64 + 4 * l + 0) * 2 + 0] + r.y * Wcs[(64 + 4 * l + 1) * 2 + 0] +
                r.z * Wcs[(64 + 4 * l + 2) * 2 + 0] + r.w * Wcs[(64 + 4 * l + 3) * 2 + 0];
    float pv1 = r.x * Wcs[(64 + 4 * l + 0) * 2 + 1] + r.y * Wcs[(64 + 4 * l + 1) * 2 + 1] +
                r.z * Wcs[(64 + 4 * l + 2) * 2 + 1] + r.w * Wcs[(64 + 4 * l + 3) * 2 + 1];
#pragma unroll
    for (int o = 1; o < 16; o <<= 1) {
      pu0 += __shfl_xor(pu0, o);
      pu1 += __shfl_xor(pu1, o);
      pv0 += __shfl_xor(pv0, o);
      pv1 += __shfl_xor(pv1, o);
    }
    if (lane == 0) {
      float4 o4 = make_float4(pu0, pu1, pv0, pv1);
      *((float4*)(uv + (size_t)wid * 4)) = o4;
    }
  }
}

// ---------------------------------------------------------------------------
// probs[e] = sigmoid(u(s) + v(d) + bc)  — factorized classifier, 16 B loads
// from the 1.6 MB L2-resident uv table.
// ---------------------------------------------------------------------------
__global__ __launch_bounds__(256) void classify_kernel(
    const float* __restrict__ uv, const int* __restrict__ ei,
    const float* __restrict__ bc, float* __restrict__ out) {
  int e = blockIdx.x * 256 + threadIdx.x;
  if (e >= E_QQ) return;
  int s = ei[e];
  int d = ei[E_QQ + e];
  float4 us = *((const float4*)(uv + (size_t)s * 4));
  float4 vd = *((const float4*)(uv + (size_t)d * 4));
  float l0 = us.x + vd.z + bc[0];
  float l1 = us.y + vd.w + bc[1];
  float2 o;
  o.x = 1.0f / (1.0f + __expf(-l0));
  o.y = 1.0f / (1.0f + __expf(-l1));
  *((float2*)(out + (size_t)e * 2)) = o;
}

extern "C" void kernel_launch(void* const* d_in, const int* in_sizes, int n_in,
                              void* d_out, int out_size, void* d_ws,
                              size_t ws_size, hipStream_t stream) {
  const float* x   = (const float*)d_in[0];
  const float* W0p = (const float*)d_in[1];
  const float* b0p = (const float*)d_in[2];
  const float* W0n = (const float*)d_in[3];
  const float* b0n = (const float*)d_in[4];
  const float* W1p = (const float*)d_in[5];
  const float* b1p = (const float*)d_in[6];
  const float* W1n = (const float*)d_in[7];
  const float* b1n = (const float*)d_in[8];
  const float* Wc  = (const float*)d_in[9];
  const float* bc  = (const float*)d_in[10];
  const int* sp = (const int*)d_in[11];
  const int* dp = (const int*)d_in[12];
  const int* sn = (const int*)d_in[13];
  const int* dn = (const int*)d_in[14];
  const int* ei = (const int*)d_in[15];

  // workspace layout (~53 MB)
  float* csrc_p = (float*)d_ws;                       // N
  float* csrc_n = csrc_p + N_NODES;                   // N
  int* offs_p = (int*)(csrc_n + N_NODES);             // N
  int* deg_p  = offs_p + N_NODES;                     // N
  int* offs_n = deg_p + N_NODES;                      // N
  int* deg_n  = offs_n + N_NODES;                     // N
  float* uv   = (float*)(deg_n + N_NODES);            // 4N
  int* gcur   = (int*)(uv + 4 * N_NODES);             // 2*NBUCK (+pad)
  unsigned* bin_d = (unsigned*)(gcur + 2 * NBUCK + 2);       // NBUCK*BCAP
  unsigned* bin_s = bin_d + (size_t)NBUCK * BCAP;            // NBUCK*BCAP
  int* srclist = (int*)(bin_s + (size_t)NBUCK * BCAP);       // NBUCK*BCAP
  __half* A = (__half*)(srclist + (size_t)NBUCK * BCAP);     // N*64 fp16
  __half* B = A + (size_t)N_NODES * 64;                      // N*64 fp16

  float* z     = (float*)d_out;                   // N*64 fp32
  float* probs = z + (size_t)N_NODES * 64;        // E_Q*2 fp32

  int* gcur_d = gcur;
  int* gcur_s = gcur + NBUCK;

  const int gemmGrid = (N_NODES + 255) / 256;
  const int aggGrid  = (N_NODES * 64 + 255) / 256;

  // ---- POS relation ----
  hipMemsetAsync(gcur, 0, 2 * NBUCK * sizeof(int), stream);
  bin_edges<<<P1_BLOCKS, 256, 0, stream>>>(sp, dp, gcur_d, gcur_s, bin_d, bin_s);
  build_tables<<<2 * NBUCK, 256, 0, stream>>>(bin_d, gcur_d, bin_s, gcur_s,
                                              offs_p, deg_p, srclist, csrc_p);
  gemm_in_h<<<gemmGrid, 256, 0, stream>>>(x, W0p, csrc_p, A);
  gather_mid<<<aggGrid, 256, 0, stream>>>(A, offs_p, deg_p, srclist, b0p,
                                          csrc_p, W1p, B);
  gather_fin<0><<<aggGrid, 256, 0, stream>>>(B, offs_p, deg_p, srclist, b1p, z,
                                             uv, Wc);

  // ---- NEG relation ---- (bins/srclist reused; pos consumers done)
  hipMemsetAsync(gcur, 0, 2 * NBUCK * sizeof(int), stream);
  bin_edges<<<P1_BLOCKS, 256, 0, stream>>>(sn, dn, gcur_d, gcur_s, bin_d, bin_s);
  build_tables<<<2 * NBUCK, 256, 0, stream>>>(bin_d, gcur_d, bin_s, gcur_s,
                                              offs_n, deg_n, srclist, csrc_n);
  gemm_in_h<<<gemmGrid, 256, 0, stream>>>(x, W0n, csrc_n, A);
  gather_mid<<<aggGrid, 256, 0, stream>>>(A, offs_n, deg_n, srclist, b0n,
                                          csrc_n, W1n, B);
  gather_fin<1><<<aggGrid, 256, 0, stream>>>(B, offs_n, deg_n, srclist, b1n, z,
                                             uv, Wc);

  // ---- classifier (factorized) ----
  classify_kernel<<<(E_QQ + 255) / 256, 256, 0, stream>>>(uv, ei, bc, probs);
}